// Round 23
// baseline (364.602 us; speedup 1.0000x reference)
//
#include <hip/hip_runtime.h>

typedef unsigned short u16;
typedef unsigned int u32;
typedef __attribute__((ext_vector_type(8))) short bf16x8;
typedef __attribute__((ext_vector_type(4))) float f32x4;
typedef __attribute__((ext_vector_type(4))) u32 u32x4;

#define DEVI static __device__ __forceinline__

// ---------------- ws layout (bytes), lifetimes verified vs launch order ----------------
constexpr size_t OFF_WTQKV = 0;                       // bf16 [1536][512] (wq^T|wk^T|wv^T)
constexpr size_t OFF_G1T   = 1572864;                 // bf16 [128][512] (contiguous after WTQKV)
constexpr size_t OFF_G2T   = OFF_G1T + 131072;        // bf16 [8][128]
constexpr size_t OFF_WCT   = OFF_G2T + 2048;          // bf16 [3][512][512]
constexpr size_t OFF_F1T   = OFF_WCT + 1572864;       // bf16 [2048][512]
constexpr size_t OFF_F2T   = OFF_F1T + 2097152;       // bf16 [512][2048]
constexpr size_t OFF_W1R   = OFF_F2T + 2097152;       // bf16 wh[64][2560] | wl[64][2560]
constexpr size_t OFF_W2R   = OFF_W1R + 655360;        // f32 [192][64]   ((d*3+k) x c)
constexpr size_t OFF_H1    = OFF_W2R + 49152;         // (slack; GMID aliases here later)
constexpr size_t OFF_GMID  = OFF_H1;                  // bf16 [8192][128]
constexpr size_t OFF_GATES = OFF_H1 + 2097152;        // f32 [8192][8]
constexpr size_t OFF_X1    = OFF_GATES + 262144;      // f32 [8192][512]
constexpr size_t OFF_X3    = OFF_X1;                  // alias: x1 dead after ln1
constexpr size_t OFF_X1B   = OFF_X1 + 16777216;       // bf16 [8192][512]
constexpr size_t OFF_FMID  = OFF_X1B;                 // bf16 [8192][2048]
constexpr size_t OFF_Q     = OFF_X1B + 8388608;       // bf16 [8192][512]
constexpr size_t OFF_H1P   = OFF_Q;                   // f32 [4][8][1024][64] partials
constexpr size_t OFF_K     = OFF_Q + 8388608;         // bf16 [8192][512]
constexpr size_t OFF_XH    = OFF_K;                   // bf16 [8][1028][512] padded x-hi
constexpr size_t OFF_VT    = OFF_K + 8388608;         // bf16 [8][8][64][1024]
constexpr size_t OFF_XL    = OFF_VT + 32768;          // bf16 [8][1028][512] padded x-lo
constexpr size_t OFF_AO    = OFF_VT + 8388608;        // f32 [8192][512]
constexpr size_t OFF_CONV  = OFF_AO;                  // alias
constexpr size_t OFF_FP0   = OFF_AO;                  // alias: ffn2 split-K partial 0
constexpr size_t OFF_X2    = OFF_AO + 16777216;       // f32 [8192][512]
constexpr size_t OFF_FP1   = OFF_X2;                  // alias: ffn2 split-K partial 1
constexpr size_t OFF_X2B   = OFF_X2 + 16777216;       // bf16 [8192][512]
constexpr size_t OFF_X3B   = OFF_X2B;                 // alias
// total ws need = OFF_X2B + 8388608 = 102,811,648 bytes (~98 MB)

DEVI u16 f2bf(float f) {
  u32 u = __builtin_bit_cast(u32, f);
  u32 r = (u + 0x7FFFu + ((u >> 16) & 1u)) >> 16;
  return (u16)r;
}
DEVI float bf2f(u16 h) { u32 u = ((u32)h) << 16; return __builtin_bit_cast(float, u); }

DEVI void load8(const float* __restrict__ p, float o[8]) {
  const float4* q = (const float4*)p;
  float4 a = q[0], b = q[1];
  o[0]=a.x; o[1]=a.y; o[2]=a.z; o[3]=a.w; o[4]=b.x; o[5]=b.y; o[6]=b.z; o[7]=b.w;
}
DEVI void store8(float* __restrict__ p, const float o[8]) {
  float4 a; a.x=o[0]; a.y=o[1]; a.z=o[2]; a.w=o[3];
  float4 b; b.x=o[4]; b.y=o[5]; b.z=o[6]; b.w=o[7];
  float4* q = (float4*)p; q[0]=a; q[1]=b;
}
DEVI void store8bf(u16* __restrict__ p, const float o[8]) {
  u32 w[4];
#pragma unroll
  for (int i=0;i<4;i++) w[i] = (u32)f2bf(o[2*i]) | ((u32)f2bf(o[2*i+1]) << 16);
  u32x4 v; v.x=w[0]; v.y=w[1]; v.z=w[2]; v.w=w[3];
  *(u32x4*)p = v;
}

// async global->LDS, 16 bytes per lane; LDS dest = wave-uniform base + lane*16
DEVI void gl_lds16(const u16* g, u16* l) {
  __builtin_amdgcn_global_load_lds((const __attribute__((address_space(1))) u32*)g,
                                   (__attribute__((address_space(3))) u32*)l, 16, 0, 0);
}

// counted-vmcnt pipeline fences (T4)
#define PIPE_WAIT(N)  asm volatile("s_waitcnt vmcnt(%0)" :: "n"(N) : "memory")
#define PIPE_WAIT0()  asm volatile("s_waitcnt vmcnt(0)" ::: "memory")
#define PIPE_BAR()    do { __builtin_amdgcn_s_barrier(); asm volatile("" ::: "memory"); } while (0)
#define PIPE_BAR_LGKM() do { asm volatile("s_waitcnt lgkmcnt(0)" ::: "memory"); \
                             __builtin_amdgcn_s_barrier(); asm volatile("" ::: "memory"); } while (0)

// ---------------- prep_all: weight transposes + conv1 weight split + x split, one launch ----------------
// blocks [0,917): prep transpose jobs; [917,981): wprep; [981,3037): xsplit
__global__ __launch_bounds__(256) void prep_all_kernel(
    const float* s0, const float* s1, const float* s2, const float* s3, const float* s4,
    const float* s5, const float* s6, const float* s7, const float* s8, const float* s9,
    char* ws,
    const float* __restrict__ w1x, u16* __restrict__ whd, u16* __restrict__ wld,
    const float* __restrict__ x, u16* __restrict__ xh, u16* __restrict__ xl) {
  __shared__ float tile[64][65];
  int blk = blockIdx.x;
  const int tid = threadIdx.x;

  if (blk < 917) {
    // ---- prep transpose job: src [K][N] f32 -> dst [N][K] (bf16 or f32) ----
    const int jsrc[11] = {0,1,2,3,4, 5,5,5, 6,7, 9};
    const int jK[11]   = {512,512,512,512,128, 512,512,512, 512,2048, 64};
    const int jN[11]   = {512,512,512,128,8,   512,512,512, 2048,512, 192};
    const int jSo[11]  = {0,0,0,0,0, 0,262144,524288, 0,0, 0};
    const long long jDo[11] = {
      (long long)OFF_WTQKV, (long long)(OFF_WTQKV+524288), (long long)(OFF_WTQKV+1048576),
      (long long)OFF_G1T, (long long)OFF_G2T,
      (long long)OFF_WCT, (long long)(OFF_WCT+524288), (long long)(OFF_WCT+1048576),
      (long long)OFF_F1T, (long long)OFF_F2T, (long long)OFF_W2R};
    const int jF[11]   = {0,0,0,0,0,0,0,0,0,0,1};

    int j = 0, t = 0;
    for (int i = 0; i < 11; i++) {
      int cnt = ((jK[i] + 63) >> 6) * ((jN[i] + 63) >> 6);
      if (blk < cnt) { j = i; t = blk; break; }
      blk -= cnt;
    }
    int K = jK[j], N = jN[j];
    int ktiles = (K + 63) >> 6;
    int k0 = (t % ktiles) << 6, n0 = (t / ktiles) << 6;
    const float* SS[10] = {s0,s1,s2,s3,s4,s5,s6,s7,s8,s9};
    const float* src = SS[jsrc[j]] + jSo[j];
    for (int i = tid; i < 4096; i += 256) {
      int r = i >> 6, c = i & 63;
      float v = 0.f;
      if (k0 + r < K && n0 + c < N) v = src[(size_t)(k0 + r) * N + n0 + c];
      tile[r][c] = v;
    }
    __syncthreads();
    if (jF[j]) {
      float* dst = (float*)(ws + jDo[j]);
      for (int i = tid; i < 4096; i += 256) {
        int nr = i >> 6, kc = i & 63;
        if (n0 + nr < N && k0 + kc < K) dst[(size_t)(n0 + nr) * K + k0 + kc] = tile[kc][nr];
      }
    } else {
      u16* dst = (u16*)(ws + jDo[j]);
      for (int i = tid; i < 4096; i += 256) {
        int nr = i >> 6, kc = i & 63;
        if (n0 + nr < N && k0 + kc < K) dst[(size_t)(n0 + nr) * K + k0 + kc] = f2bf(tile[kc][nr]);
      }
    }
    return;
  }
  blk -= 917;
  if (blk < 64) {
    // ---- wprep: w1 [64][512][5] -> wh/wl bf16 [64][k*512+d] ----
    int c = blk;
    for (int kk = tid; kk < 2560; kk += 256) {
      int k = kk >> 9, d = kk & 511;
      float v = w1x[(size_t)c * 2560 + d * 5 + k];
      u16 h = f2bf(v);
      whd[(size_t)c * 2560 + kk] = h;
      wld[(size_t)c * 2560 + kk] = f2bf(v - bf2f(h));
    }
    return;
  }
  blk -= 64;
  // ---- xsplit: x [8][1024][512] -> padded bf16 hi/lo [8][1028][512] ----
  {
    int idx = blk * 256 + tid;
    if (idx >= 8 * 1028 * 64) return;
    int r = idx >> 6;
    int col = (idx & 63) * 8;
    int b = r / 1028, rr = r % 1028;
    size_t dof = ((size_t)r) * 512 + col;
    if (rr < 2 || rr >= 1026) {
      u32x4 z; z.x = 0; z.y = 0; z.z = 0; z.w = 0;
      *(u32x4*)&xh[dof] = z;
      *(u32x4*)&xl[dof] = z;
      return;
    }
    const float* src = x + (((size_t)b << 10) + rr - 2) * 512 + col;
    float v[8];
    load8(src, v);
    u32 ph[4], pl[4];
#pragma unroll
    for (int i = 0; i < 4; i++) {
      u16 h0 = f2bf(v[2 * i]),     l0 = f2bf(v[2 * i]     - bf2f(f2bf(v[2 * i])));
      u16 h1 = f2bf(v[2 * i + 1]), l1 = f2bf(v[2 * i + 1] - bf2f(f2bf(v[2 * i + 1])));
      ph[i] = (u32)h0 | ((u32)h1 << 16);
      pl[i] = (u32)l0 | ((u32)l1 << 16);
    }
    u32x4 H; H.x=ph[0]; H.y=ph[1]; H.z=ph[2]; H.w=ph[3];
    u32x4 L; L.x=pl[0]; L.y=pl[1]; L.z=pl[2]; L.w=pl[3];
    *(u32x4*)&xh[dof] = H;
    *(u32x4*)&xl[dof] = L;
  }
}

// ---------------- conv1 v8: MFMA split-bf16 GEMM, 3-buffer depth-2 pipeline, 6 blocks/CU ----------------
__global__ __launch_bounds__(256, 6) void conv1g_kernel(
    const u16* __restrict__ xh, const u16* __restrict__ xl,
    const u16* __restrict__ wh, const u16* __restrict__ wl,
    float* __restrict__ h1p) {
  __shared__ alignas(16) u16 a_s[3][64 * 32];
  __shared__ alignas(16) u16 b_s[3][64 * 32];
  const int tid = threadIdx.x, lane = tid & 63, wid = tid >> 6;
  const int m0 = blockIdx.x * 64;
  const int z = blockIdx.z;
  const int wr = wid >> 1, wc = wid & 1;
  const int mb = wr * 32, nb = wc * 32;
  const int lrow = lane & 15, lk = (lane >> 4) * 8;
  const int lr4 = lane >> 2, lc8 = (lane & 3) * 8;
  const int bb = m0 >> 10, lblk = m0 & 1023;
  const size_t xrow0 = (size_t)bb * 1028;

  auto stage = [&](int buf, int kk) {
    int p = (kk >= 5120) ? 2 : (kk >= 2560) ? 1 : 0;
    int kpp = kk - p * 2560;
    int ktap = kpp >> 9, d0 = kpp & 511;
    const u16* xa = (p == 1) ? xl : xh;
    const u16* wb = (p == 2) ? wl : wh;
    gl_lds16(&xa[(xrow0 + lblk + wid * 16 + lr4 + ktap) * 512 + d0 + lc8],
             &a_s[buf][wid * 512]);
    gl_lds16(&wb[(size_t)(wid * 16 + lr4) * 2560 + kpp + lc8],
             &b_s[buf][wid * 512]);
  };

  f32x4 acc[2][2];
#pragma unroll
  for (int m = 0; m < 2; m++)
#pragma unroll
    for (int n = 0; n < 2; n++) { acc[m][n].x=0.f; acc[m][n].y=0.f; acc[m][n].z=0.f; acc[m][n].w=0.f; }

  const int kz0 = z * 1920, kz1 = kz0 + 1920;
  stage(0, kz0);
  stage(1, kz0 + 32);
  int cur = 0;
  for (int kk = kz0; kk < kz1; kk += 32) {
    if (kk + 64 < kz1) {
      int stg = cur - 1; if (stg < 0) stg = 2;   // (cur+2)%3
      stage(stg, kk + 64);
      PIPE_WAIT(4);
    } else if (kk + 32 < kz1) {
      PIPE_WAIT(2);
    } else {
      PIPE_WAIT0();
    }
    PIPE_BAR();
    bf16x8 af[2], bfr[2];
#pragma unroll
    for (int m = 0; m < 2; m++) af[m]  = *(const bf16x8*)&a_s[cur][(mb + m * 16 + lrow) * 32 + lk];
#pragma unroll
    for (int n = 0; n < 2; n++) bfr[n] = *(const bf16x8*)&b_s[cur][(nb + n * 16 + lrow) * 32 + lk];
#pragma unroll
    for (int m = 0; m < 2; m++)
#pragma unroll
      for (int n = 0; n < 2; n++)
        acc[m][n] = __builtin_amdgcn_mfma_f32_16x16x32_bf16(af[m], bfr[n], acc[m][n], 0, 0, 0);
    PIPE_BAR_LGKM();
    cur = (cur == 2) ? 0 : cur + 1;
  }
  const int r4 = (lane >> 4) * 4;
#pragma unroll
  for (int m = 0; m < 2; m++) {
#pragma unroll
    for (int n = 0; n < 2; n++) {
      const int col = nb + n * 16 + lrow;
#pragma unroll
      for (int j = 0; j < 4; j++) {
        const int row = m0 + mb + m * 16 + r4 + j;
        h1p[(size_t)z * 524288 + (size_t)row * 64 + col] = acc[m][n][j];
      }
    }
  }
}

// ------- conv23 v2: 16-l blocks (512), wave-parallel conv3, vectorized emb-add -------
__global__ __launch_bounds__(256) void conv23_kernel(
    const float* __restrict__ h1p, const float* __restrict__ b1,
    const float* __restrict__ w2r, const float* __restrict__ b2,
    const float* __restrict__ w3, const float* __restrict__ b3,
    const float* __restrict__ x, const float* __restrict__ emb,
    float* __restrict__ wmOut, float* __restrict__ x1, u16* __restrict__ x1b) {
  int seg = blockIdx.x;
  int batch = seg >> 6, l0 = (seg & 63) << 4;
  int tid = threadIdx.x, lane = tid & 63, wave = tid >> 6;
  __shared__ float hs[20][64];
  __shared__ float h2s[18][65];
  __shared__ float w3s[576];
  __shared__ int labS[16];
  for (int i = tid; i < 20 * 64; i += 256) {
    int r = i >> 6, cc = i & 63;
    int lp = l0 - 2 + r;
    float v = 0.f;
    if (lp >= 0 && lp < 1024) {
      size_t base = ((size_t)batch * 1024 + lp) * 64 + cc;
      float s = b1[cc];
#pragma unroll
      for (int q = 0; q < 4; q++) s += h1p[base + (size_t)q * 524288];
      v = fmaxf(s, 0.f);
    }
    hs[r][cc] = v;
  }
  for (int i = tid; i < 576; i += 256) w3s[i] = w3[i];
  __syncthreads();
  {
    int c = lane;
    int r0 = wave * 5;
    float a2[5];
#pragma unroll
    for (int i = 0; i < 5; i++) a2[i] = b2[c];
    for (int dd = 0; dd < 64; dd++) {
      float xv[7];
#pragma unroll
      for (int i = 0; i < 7; i++) xv[i] = (r0 + i < 20) ? hs[r0 + i][dd] : 0.f;
#pragma unroll
      for (int k = 0; k < 3; k++) {
        float wv = w2r[(size_t)(dd * 3 + k) * 64 + c];
#pragma unroll
        for (int i = 0; i < 5; i++) a2[i] += xv[i + k] * wv;
      }
    }
#pragma unroll
    for (int i = 0; i < 5; i++) {
      int hr = r0 + i;
      if (hr < 18) h2s[hr][c] = fmaxf(a2[i], 0.f);
    }
  }
  __syncthreads();
  {
    int li = tid >> 4, g = tid & 15;
    int c0 = g * 4;
    float wp[3];
#pragma unroll
    for (int jw = 0; jw < 3; jw++) {
      float a = 0.f;
#pragma unroll
      for (int k = 0; k < 3; k++)
#pragma unroll
        for (int c = 0; c < 4; c++)
          a += h2s[li + k][c0 + c] * w3s[(jw * 64 + c0 + c) * 3 + k];
      wp[jw] = a;
    }
#pragma unroll
    for (int d = 1; d < 16; d <<= 1) {
#pragma unroll
      for (int jw = 0; jw < 3; jw++) wp[jw] += __shfl_xor(wp[jw], d);
    }
    if (g == 0) {
      float wp0 = wp[0] + b3[0], wp1 = wp[1] + b3[1], wp2 = wp[2] + b3[2];
      float mx = fmaxf(wp0, fmaxf(wp1, wp2));
      float e0 = __expf(wp0 - mx), e1 = __expf(wp1 - mx), e2 = __expf(wp2 - mx);
      float inv = 1.f / (e0 + e1 + e2);
      size_t mo = ((size_t)batch * 1024 + l0 + li) * 3;
      wmOut[mo] = e0 * inv; wmOut[mo + 1] = e1 * inv; wmOut[mo + 2] = e2 * inv;
      int lb = 0; float bv = wp0;
      if (wp1 > bv) { bv = wp1; lb = 1; }
      if (wp2 > bv) { lb = 2; }
      labS[li] = lb;
    }
  }
  __syncthreads();
  for (int i = tid; i < 16 * 128; i += 256) {
    int r = i >> 7, cq = (i & 127) << 2;
    size_t gi = ((size_t)batch * 1024 + l0 + r) * 512 + cq;
    float4 xv = *(const float4*)&x[gi];
    const float* ep = &emb[(size_t)labS[r] * 512 + cq];
    float4 ev = *(const float4*)ep;
    float4 v; v.x = xv.x + ev.x; v.y = xv.y + ev.y; v.z = xv.z + ev.z; v.w = xv.w + ev.w;
    *(float4*)&x1[gi] = v;
    u32 lo = (u32)f2bf(v.x) | ((u32)f2bf(v.y) << 16);
    u32 hi = (u32)f2bf(v.z) | ((u32)f2bf(v.w) << 16);
    *(u32*)&x1b[gi] = lo;
    *(u32*)&x1b[gi + 2] = hi;
  }
}

// ---------------- generic bf16 MFMA GEMM v12: 2-buffer flat smem, 5 blocks/CU, wavesim front ----------------
struct GemmArgs {
  const u16* A; const u16* Bt;
  int lda; int ldb; int K;
  const float* bias;
  u16* obf; int ldo;
  float* of32; int ldo32;
  u16* Qo; u16* Ko; u16* Vto;
  const float* bq; const float* bk; const float* bv;
  const float* wmS; float* adjS;   // fused wavesim (EPI 3, blockIdx.y == 0)
};

// EPI: 1=bias+relu->bf16, 2=bias->f32,
//      3=QKV+gates scatter (V via LDS-transpose); blockIdx.y==0 -> wavesim branch, GEMM n0=(y-1)*BN
//      6=split-K partial f32
template<int BM, int BN, int FM, int FN, int EPI>
__global__ __launch_bounds__(256, 5) void gemm_k(GemmArgs p) {
  __shared__ alignas(16) char smem[32768];   // 2 A-bufs (16KB) + 2 B-bufs (16KB); reused for V-transpose / wavesim
  u16* aS = (u16*)smem;
  u16* bS = aS + 2 * BM * 32;
  const int tid = threadIdx.x;
  const int lane = tid & 63, wid = tid >> 6;

  if constexpr (EPI == 3) {
    if (blockIdx.y == 0) {
      // ---- fused wavesim: adj[b] = wm[b] @ wm[b]^T, 64 blocks (8 b x 8 row-segs of 128) ----
      float* ms = (float*)smem;                       // [1024*3] = 12KB
      const int b = blockIdx.x >> 3;
      const int r0 = (blockIdx.x & 7) << 7;
      for (int i = tid; i < 3072; i += 256) ms[i] = p.wmS[(size_t)b * 3072 + i];
      __syncthreads();
      const int m0q = tid * 4;
      float c0 = ms[(m0q + 0) * 3],     c1 = ms[(m0q + 1) * 3],     c2 = ms[(m0q + 2) * 3],     c3 = ms[(m0q + 3) * 3];
      float d0 = ms[(m0q + 0) * 3 + 1], d1 = ms[(m0q + 1) * 3 + 1], d2 = ms[(m0q + 2) * 3 + 1], d3 = ms[(m0q + 3) * 3 + 1];
      float e0 = ms[(m0q + 0) * 3 + 2], e1 = ms[(m0q + 1) * 3 + 2], e2 = ms[(m0q + 2) * 3 + 2], e3 = ms[(m0q + 3) * 3 + 2];
      for (int r = 0; r < 128; r++) {
        float a0 = ms[(r0 + r) * 3], a1 = ms[(r0 + r) * 3 + 1], a2 = ms[(r0 + r) * 3 + 2];
        f32x4 v;
        v.x = a0 * c0 + a1 * d0 + a2 * e0;
        v.y = a0 * c1 + a1 * d1 + a2 * e1;
        v.z = a0 * c2 + a1 * d2 + a2 * e2;
        v.w = a0 * c3 + a1 * d3 + a2 * e3;
        __builtin_nontemporal_store(v, (f32x4*)&p.adjS[((size_t)b * 1024 + r0 + r) * 1024 + m0q]);
      }
      return;
    }
  }

  const int m0 = blockIdx.x * BM;
  const int n0 = (EPI == 3) ? (blockIdx.y - 1) * BN : blockIdx.y * BN;
  const int koff = (EPI == 6) ? blockIdx.z * p.K : 0;
  const int wr = wid >> 1, wc = wid & 1;
  const int mb = wr * (FM * 16), nb = wc * (FN * 16);
  const int lrow = lane & 15, lk = (lane >> 4) * 8;
  constexpr int CPW_A = BM / 64;
  constexpr int CPW_B = BN / 64;
  constexpr int NL = CPW_A + CPW_B;
  const int lr4 = lane >> 2, lc8 = (lane & 3) * 8;

  auto stage = [&](int buf, int k0) {
#pragma unroll
    for (int j = 0; j < CPW_A; j++) {
      int chunk = wid * CPW_A + j;
      gl_lds16(&p.A[(size_t)(m0 + chunk * 16 + lr4) * p.lda + koff + k0 + lc8],
               &aS[buf * BM * 32 + chunk * 512]);
    }
#pragma unroll
    for (int j = 0; j < CPW_B; j++) {
      int chunk = wid * CPW_B + j;
      gl_lds16(&p.Bt[(size_t)(n0 + chunk * 16 + lr4) * p.ldb + koff + k0 + lc8],
               &bS[buf * BN * 32 + chunk * 512]);
    }
  };

  f32x4 acc[FM][FN];
#pragma unroll
  for (int m = 0; m < FM; m++)
#pragma unroll
    for (int n = 0; n < FN; n++) { acc[m][n].x=0.f; acc[m][n].y=0.f; acc[m][n].z=0.f; acc[m][n].w=0.f; }

  stage(0, 0);
  int cur = 0;
  for (int k0 = 0; k0 < p.K; k0 += 32) {
    if (k0 + 32 < p.K) {
      stage(cur ^ 1, k0 + 32);
      PIPE_WAIT(NL);
    } else {
      PIPE_WAIT0();
    }
    PIPE_BAR();
    bf16x8 af[FM], bfr[FN];
#pragma unroll
    for (int m = 0; m < FM; m++)
      af[m] = *(const bf16x8*)&aS[cur * BM * 32 + (mb + m * 16 + lrow) * 32 + lk];
#pragma unroll
    for (int n = 0; n < FN; n++)
      bfr[n] = *(const bf16x8*)&bS[cur * BN * 32 + (nb + n * 16 + lrow) * 32 + lk];
#pragma unroll
    for (int m = 0; m < FM; m++)
#pragma unroll
      for (int n = 0; n < FN; n++)
        acc[m][n] = __builtin_amdgcn_mfma_f32_16x16x32_bf16(af[m], bfr[n], acc[m][n], 0, 0, 0);
    PIPE_BAR_LGKM();
    cur ^= 1;
  }
  const int r4 = (lane >> 4) * 4;

  if constexpr (EPI == 3) {
    if (n0 >= 1024 && n0 < 1536) {
      // ---- V-region block: LDS-transpose + coalesced bf16 stores ----
      float* ts = (float*)smem;              // [64 cols][128 rows], chunk-XOR swizzled (32KB exact)
      const int bb = m0 >> 10, lblk = m0 & 1023;
#pragma unroll
      for (int H = 0; H < 2; H++) {
        __syncthreads();
        if (wc == H) {
#pragma unroll
          for (int m = 0; m < FM; m++) {
#pragma unroll
            for (int n = 0; n < FN; n++) {
              const int c = n * 16 + lrow;
              const int cc = (n0 - 1024) + H * 64 + c;
              const float bvv = p.bv[cc];
#pragma unroll
              for (int j = 0; j < 4; j++) {
                const int r = mb + m * 16 + r4 + j;
                ts[c * 128 + (r ^ ((c & 3) << 2))] = acc[m][n][j] + bvv;
              }
            }
          }
        }
        __syncthreads();
        const int c = tid >> 2, seg = tid & 3;
        const int cc = (n0 - 1024) + H * 64 + c;
        const int hh = cc >> 6, dd = cc & 63;
        u16* dst = &p.Vto[((((size_t)bb * 8 + hh) * 64 + dd) << 10) + lblk + seg * 32];
        u32 pk[16];
#pragma unroll
        for (int j = 0; j < 8; j++) {
          const int chunk = seg * 8 + j;
          f32x4 v4 = *(const f32x4*)&ts[c * 128 + ((chunk ^ (c & 3)) << 2)];
          pk[2 * j + 0] = (u32)f2bf(v4.x) | ((u32)f2bf(v4.y) << 16);
          pk[2 * j + 1] = (u32)f2bf(v4.z) | ((u32)f2bf(v4.w) << 16);
        }
#pragma unroll
        for (int q = 0; q < 4; q++) {
          u32x4 sv; sv.x = pk[4 * q]; sv.y = pk[4 * q + 1]; sv.z = pk[4 * q + 2]; sv.w = pk[4 * q + 3];
          *(u32x4*)&dst[q * 8] = sv;
        }
      }
      return;
    }
  }

#pragma unroll
  for (int m = 0; m < FM; m++) {
#pragma unroll
    for (int n = 0; n < FN; n++) {
      const int col = n0 + nb + n * 16 + lrow;
#pragma unroll
      for (int j = 0; j < 4; j++) {
        const int row = m0 + mb + m * 16 + r4 + j;
        float v = acc[m][n][j];
        if constexpr (EPI == 1) {
          v += p.bias[col];
          v = fmaxf(v, 0.f);
          p.obf[(size_t)row * p.ldo + col] = f2bf(v);
        } else if constexpr (EPI == 2) {
          v += p.bias[col];
          p.of32[(size_t)row * p.ldo32 + col] = v;
        } else if constexpr (EPI == 3) {
          if (col < 512) {
            v += p.bq[col];
            p.Qo[(size_t)row * 512 + col] = f2bf(v);
          } else if (col < 1024) {
            int cc = col - 512;
            v += p.bk[cc];
            p.Ko[(size_t)row * 512 + cc] = f2bf(v);
          } else if (col >= 1536) {
            int cc = col - 1536;
            v += p.bias[cc];
            v = fmaxf(v, 0.f);
            p.obf[(size_t)row * 128 + cc] = f2bf(v);
          }
        } else if constexpr (EPI == 6) {
          if (blockIdx.z == 0) v += p.bias[col];
          p.of32[(size_t)blockIdx.z * p.ldo32 + (size_t)row * 512 + col] = v;
        }
      }
    }
  }
}

// ---------------- fused wc GEMM v5: 2-buffer counted-vmcnt pipeline (unhinted) ----------------
__global__ __launch_bounds__(256) void wcg_kernel(
    const u16* __restrict__ A, const u16* __restrict__ Wct,
    const float* __restrict__ wcb, const float* __restrict__ wmask,
    const float* __restrict__ wwts, float* __restrict__ out) {
  __shared__ alignas(16) u16 a_s[2][128 * 32];
  __shared__ alignas(16) u16 b_s[2][3 * 64 * 32];
  const int tid = threadIdx.x, lane = tid & 63, wid = tid >> 6;
  const int m0 = blockIdx.x * 128, n0 = blockIdx.y * 64;
  const int wr = wid >> 1, wc = wid & 1;
  const int mb = wr * 64, nb = wc * 32;
  const int lrow = lane & 15, lk = (lane >> 4) * 8;
  const int lr4 = lane >> 2, lc8 = (lane & 3) * 8;

  auto stage = [&](int buf, int k0) {
#pragma unroll
    for (int t = 0; t < 2; t++) {
      int ch = wid * 2 + t;
      gl_lds16(&A[(size_t)(m0 + ch * 16 + lr4) * 512 + k0 + lc8], &a_s[buf][ch * 512]);
    }
#pragma unroll
    for (int t = 0; t < 3; t++) {
      int ch = wid * 3 + t;
      int wI = ch >> 2, sub = ch & 3;
      gl_lds16(&Wct[(size_t)wI * 262144 + (size_t)(n0 + sub * 16 + lr4) * 512 + k0 + lc8],
               &b_s[buf][ch * 512]);
    }
  };

  f32x4 acc[4][2][3];
#pragma unroll
  for (int m = 0; m < 4; m++)
#pragma unroll
    for (int n = 0; n < 2; n++)
#pragma unroll
      for (int w = 0; w < 3; w++) { acc[m][n][w].x=0.f; acc[m][n][w].y=0.f; acc[m][n][w].z=0.f; acc[m][n][w].w=0.f; }

  stage(0, 0);
  int cur = 0;
  for (int k0 = 0; k0 < 512; k0 += 32) {
    if (k0 + 32 < 512) {
      stage(cur ^ 1, k0 + 32);
      PIPE_WAIT(5);
    } else {
      PIPE_WAIT0();
    }
    PIPE_BAR();
    bf16x8 af[4], bfr[3][2];
#pragma unroll
    for (int m = 0; m < 4; m++) af[m] = *(const bf16x8*)&a_s[cur][(mb + m * 16 + lrow) * 32 + lk];
#pragma unroll
    for (int w = 0; w < 3; w++)
#pragma unroll
      for (int n = 0; n < 2; n++)
        bfr[w][n] = *(const bf16x8*)&b_s[cur][(w * 64 + nb + n * 16 + lrow) * 32 + lk];
#pragma unroll
    for (int m = 0; m < 4; m++)
#pragma unroll
      for (int n = 0; n < 2; n++)
#pragma unroll
        for (int w = 0; w < 3; w++)
          acc[m][n][w] = __builtin_amdgcn_mfma_f32_16x16x32_bf16(af[m], bfr[w][n], acc[m][n][w], 0, 0, 0);
    PIPE_BAR_LGKM();
    cur ^= 1;
  }
  const float w0 = wwts[0], w1 = wwts[1], w2 = wwts[2];
  const int r4 = (lane >> 4) * 4;
#pragma unroll
  for (int m = 0; m < 4; m++) {
#pragma unroll
    for (int j = 0; j < 4; j++) {
      const int row = m0 + mb + m * 16 + r4 + j;
      float c0 = wmask[(size_t)row * 3 + 0] * w0;
      float c1 = wmask[(size_t)row * 3 + 1] * w1;
      float c2 = wmask[(size_t)row * 3 + 2] * w2;
#pragma unroll
      for (int n = 0; n < 2; n++) {
        const int col = n0 + nb + n * 16 + lrow;
        float v = c0 * (acc[m][n][0][j] + wcb[col])
                + c1 * (acc[m][n][1][j] + wcb[512 + col])
                + c2 * (acc[m][n][2][j] + wcb[1024 + col]);
        out[(size_t)row * 512 + col] = v;
      }
    }
  }
}

// ---------------- gates stage 2: sigmoid(mid @ g2 + b), N=8 ----------------
__global__ __launch_bounds__(256) void gates2_kernel(const u16* __restrict__ gmid,
    const u16* __restrict__ g2t, const float* __restrict__ g2b, float* __restrict__ gates) {
  int r0 = blockIdx.x * 64;
  __shared__ u16 ms[64][136];
  __shared__ u16 gs[8][136];
  __shared__ float gb[8];
  int tid = threadIdx.x;
  for (int i = tid; i < 1024; i += 256) {
    int r = i >> 4, ch = (i & 15) * 8;
    *(bf16x8*)&ms[r][ch] = *(const bf16x8*)&gmid[(size_t)(r0 + r) * 128 + ch];
  }
  if (tid < 128) {
    int r = tid >> 4, ch = (tid & 15) * 8;
    *(bf16x8*)&gs[r][ch] = *(const bf16x8*)&g2t[(size_t)r * 128 + ch];
  }
  if (tid < 8) gb[tid] = g2b[tid];
  __syncthreads();
  for (int o = tid; o < 512; o += 256) {
    int r = o >> 3, hh = o & 7;
    float a = gb[hh];
    for (int k = 0; k < 128; k++) a += bf2f(ms[r][k]) * bf2f(gs[hh][k]);
    gates[(size_t)(r0 + r) * 8 + hh] = 1.f / (1.f + __expf(-a));
  }
}

// ---------------- fused flash attention v4: single-buffer, 4 blocks/CU hint ----------------
__global__ __launch_bounds__(256, 4) void attn_kernel(
    const u16* __restrict__ Qb, const u16* __restrict__ Kb, const u16* __restrict__ Vt,
    const float* __restrict__ gates, const float* __restrict__ wm, float* __restrict__ ao) {
  const int g = blockIdx.x & 63, qt = blockIdx.x >> 6;
  const int b = g >> 3, h = g & 7, q0 = qt << 6;
  const int tid = threadIdx.x, lane = tid & 63, w = tid >> 6;
  __shared__ alignas(16) u16 k_s[64 * 64];
  __shared__ alignas(16) u16 v_s[64 * 64];
  __shared__ u16 p_s[4][16][72];
  __shared__ float gat[64];
  __shared__ float wmk[64][4];
  const int lrow = lane & 15, lq = lane >> 4, lk = lq * 8;
  const int qrb = q0 + w * 16;
  const int sr_ = lane >> 3, sc_ = lane & 7;
  bf16x8 qf[2];
#pragma unroll
  for (int ks = 0; ks < 2; ks++)
    qf[ks] = *(const bf16x8*)&Qb[((size_t)(b * 1024 + qrb + lrow)) * 512 + h * 64 + ks * 32 + lk];
  float wq_[4][3];
#pragma unroll
  for (int j = 0; j < 4; j++) {
    int qr = qrb + lq * 4 + j;
#pragma unroll
    for (int t = 0; t < 3; t++) wq_[j][t] = wm[((size_t)b * 1024 + qr) * 3 + t];
  }
  float lsum[4];
  f32x4 oacc[4];
#pragma unroll
  for (int j = 0; j < 4; j++) lsum[j] = 0.f;
#pragma unroll
  for (int n = 0; n < 4; n++) { oacc[n].x=0.f; oacc[n].y=0.f; oacc[n].z=0.f; oacc[n].w=0.f; }

  const u16* Kbase = Kb + ((size_t)b * 1024) * 512 + h * 64;
  const u16* Vbase = Vt + ((size_t)(b * 8 + h)) * 64 * 1024;

  for (int kt = 0; kt < 16; kt++) {
    int k0 = kt * 64;
    __syncthreads();
#pragma unroll
    for (int t = 0; t < 2; t++) {
      int ch = (w << 1) | t;
      int r = (ch << 3) | sr_;
      int srcc = ((sc_ ^ (r & 7)) << 3);
      gl_lds16(&Kbase[(size_t)(k0 + r) * 512 + srcc], &k_s[ch << 9]);
      gl_lds16(&Vbase[(size_t)r * 1024 + k0 + srcc], &v_s[ch << 9]);
    }
    if (tid < 64) {
      gat[tid] = gates[((size_t)b * 1024 + k0 + tid) * 8 + h];
#pragma unroll
      for (int t = 0; t < 3; t++) wmk[tid][t] = wm[((size_t)b * 1024 + k0 + tid) * 3 + t];
    }
    __syncthreads();
    f32x4 s[4];
#pragma unroll
    for (int n = 0; n < 4; n++) { s[n].x=0.f; s[n].y=0.f; s[n].z=0.f; s[n].w=0.f; }
#pragma unroll
    for (int ks = 0; ks < 2; ks++) {
      bf16x8 kf[4];
#pragma unroll
      for (int n = 0; n < 4; n++) {
        int kr = n * 16 + lrow;
        kf[n] = *(const bf16x8*)&k_s[kr * 64 + ((((ks << 2) | lq) ^ (kr & 7)) << 3)];
      }
#pragma unroll
      for (int n = 0; n < 4; n++)
        s[n] = __builtin_amdgcn_mfma_f32_16x16x32_bf16(qf[ks], kf[n], s[n], 0, 0, 0);
    }
    float pv[4][4];
#pragma unroll
    for (int n = 0; n < 4; n++) {
      int cl = n * 16 + lrow;
      float gg = gat[cl];
      float w0 = wmk[cl][0], w1 = wmk[cl][1], w2 = wmk[cl][2];
#pragma unroll
      for (int j = 0; j < 4; j++) {
        float wsv = wq_[j][0] * w0 + wq_[j][1] * w1 + wq_[j][2] * w2;
        float sv = s[n][j] * 0.125f;
        float e = __expf(sv * (gg + wsv) + wsv);
        pv[n][j] = e;
        lsum[j] += e;
      }
    }
#pragma unroll
    for (int n = 0; n < 4; n++)
#pragma unroll
      for (int j = 0; j < 4; j++)
        p_s[w][lq * 4 + j][n * 16 + lrow] = f2bf(pv[n][j]);
#pragma unroll
    for (int ks = 0; ks < 2; ks++) {
      bf16x8 pa, vb[4];
      pa = *(const bf16x8*)&p_s[w][lrow][ks * 32 + lk];
#pragma unroll
      for (int n = 0; n < 4; n++) {
        int vr = n * 16 + lrow;
        vb[n] = *(const bf16x8*)&v_s[vr * 64 + ((((ks << 2) | lq) ^ (vr & 7)) << 3)];
      }
#pragma unroll
      for (int n = 0; n < 4; n++)
        oacc[n] = __builtin_amdgcn_mfma_f32_16x16x32_bf16(pa, vb[n], oacc[n], 0, 0, 0);
    }
  }
  float rinv[4];
#pragma unroll
  for (int j = 0; j < 4; j++) {
    float s = lsum[j];
#pragma unroll
    for (int d = 1; d < 16; d <<= 1) s += __shfl_xor(s, d);
    rinv[j] = 1.f / s;
  }
#pragma unroll
  for (int n = 0; n < 4; n++) {
    int col = h * 64 + n * 16 + lrow;
#pragma unroll
    for (int j = 0; j < 4; j++) {
      int row = b * 1024 + qrb + lq * 4 + j;
      ao[(size_t)row * 512 + col] = oacc[n][j] * rinv[j];
    }
  }
}

// ---------------- LayerNorm helpers & fused double-LN kernels ----------------
DEVI void ln512(const float u[8], const float* __restrict__ g, const float* __restrict__ b,
                int lane, float out[8]) {
  float s = 0.f;
#pragma unroll
  for (int i = 0; i < 8; i++) s += u[i];
#pragma unroll
  for (int m = 1; m < 64; m <<= 1) s += __shfl_xor(s, m);
  float mean = s * (1.f / 512.f);
  float d[8], q = 0.f;
#pragma unroll
  for (int i = 0; i < 8; i++) { d[i] = u[i] - mean; q += d[i] * d[i]; }
#pragma unroll
  for (int m = 1; m < 64; m <<= 1) q += __shfl_xor(q, m);
  float inv = rsqrtf(q * (1.f / 512.f) + 1e-5f);
  int base = lane * 8;
#pragma unroll
  for (int i = 0; i < 8; i++) out[i] = d[i] * inv * g[base + i] + b[base + i];
}

__global__ __launch_bounds__(256) void ln1_kernel(
    const float* __restrict__ ao, const float* __restrict__ x1,
    const float* __restrict__ ga, const float* __restrict__ gb,
    const float* __restrict__ n1g, const float* __restrict__ n1b,
    float* __restrict__ x2, u16* __restrict__ x2b) {
  int row = blockIdx.x * 4 + (threadIdx.x >> 6);
  int lane = threadIdx.x & 63;
  size_t base = (size_t)row * 512 + lane * 8;
  float av[8], xv[8], u[8], t[8];
  load8(ao + base, av);
  load8(x1 + base, xv);
#pragma unroll
  for (int i = 0; i < 8; i++) u[i] = av[i] + xv[i];
  ln512(u, ga, gb, lane, t);
#pragma unroll
  for (int i = 0; i < 8; i++) u[i] = xv[i] + t[i];
  ln512(u, n1g, n1b, lane, t);
  store8(x2 + base, t);
  store8bf(x2b + base, t);
}

__global__ __launch_bounds__(256) void ln2_kernel(
    const float* __restrict__ co, const float* __restrict__ x2,
    const float* __restrict__ gc, const float* __restrict__ bc,
    const float* __restrict__ n2g, const float* __restrict__ n2b,
    float* __restrict__ x3, u16* __restrict__ x3b) {
  int row = blockIdx.x * 4 + (threadIdx.x >> 6);
  int lane = threadIdx.x & 63;
  size_t base = (size_t)row * 512 + lane * 8;
  float av[8], xv[8], u[8], t[8];
  load8(co + base, av);
#pragma unroll
  for (int i = 0; i < 8; i++) u[i] = fmaxf(av[i], 0.f);
  ln512(u, gc, bc, lane, t);
  load8(x2 + base, xv);
#pragma unroll
  for (int i = 0; i < 8; i++) u[i] = xv[i] + t[i];
  ln512(u, n2g, n2b, lane, t);
  store8(x3 + base, t);
  store8bf(x3b + base, t);
}

// ln3 v2: sums the two ffn2 split-K partials (bias already in p0)
__global__ __launch_bounds__(256) void ln3_kernel(
    const float* __restrict__ x3, const float* __restrict__ p0, const float* __restrict__ p1,
    const float* __restrict__ n3g, const float* __restrict__ n3b,
    float* __restrict__ out0) {
  int row = blockIdx.x * 4 + (threadIdx.x >> 6);
  int lane = threadIdx.x & 63;
  size_t base = (size_t)row * 512 + lane * 8;
  float a0[8], a1[8], xv[8], u[8], t[8];
  load8(x3 + base, xv);
  load8(p0 + base, a0);
  load8(p1 + base, a1);
#pragma unroll
  for (int i = 0; i < 8; i++) u[i] = xv[i] + a0[i] + a1[i];
  ln512(u, n3g, n3b, lane, t);
  store8(out0 + base, t);
}

// ---------------- host launch ----------------
extern "C" void kernel_launch(void* const* d_in, const int* in_sizes, int n_in,
                              void* d_out, int out_size, void* d_ws, size_t ws_size,
                              hipStream_t stream) {
  const float* x    = (const float*)d_in[0];
  const float* w1   = (const float*)d_in[1];
  const float* c1b  = (const float*)d_in[2];
  const float* w2   = (const float*)d_in[3];
  const float* c2b  = (const float*)d_in[4];
  const float* w3   = (const float*)d_in[5];
  const float* c3b  = (const float*)d_in[6];
  const float* emb  = (const float*)d_in[7];
  const float* wqw  = (const float*)d_in[8];
  const float* wqb  = (const float*)d_in[9];
  const float* wkw  = (const float*)d_in[10];
  const float* wkb  = (const float*)d_in[11];
  const float* wvw  = (const float*)d_in[12];
  const float* wvb  = (const float*)d_in[13];
  const float* g1w  = (const float*)d_in[14];
  const float* g1b  = (const float*)d_in[15];
  const float* g2w  = (const float*)d_in[16];
  const float* g2b  = (const float*)d_in[17];
  const float* lag  = (const float*)d_in[18];
  const float* lab  = (const float*)d_in[19];
  const float* n1g  = (const float*)d_in[20];
  const float* n1b  = (const float*)d_in[21];
  const float* lcg  = (const float*)d_in[22];
  const float* lcb  = (const float*)d_in[23];
  const float* n2g  = (const float*)d_in[24];
  const float* n2b  = (const float*)d_in[25];
  const float* n3g  = (const float*)d_in[26];
  const float* n3b  = (const float*)d_in[27];
  const float* wcw  = (const float*)d_in[28];
  const float* wcb  = (const float*)d_in[29];
  const float* wwts = (const float*)d_in[30];
  const float* f1w  = (const float*)d_in[31];
  const float* f1b  = (const float*)d_in[32];
  const float* f2w  = (const float*)d_in[33];
  const float* f2b  = (const float*)d_in[34];

  char* ws = (char*)d_ws;
  float* out0 = (float*)d_out;
  float* out1 = out0 + 4194304;   // wave_mask [8,1024,3]
  float* out2 = out1 + 24576;     // subgraph_adj [8,1024,1024]

  float* w2r_p  = (float*)(ws + OFF_W2R);
  u16*   wh_p   = (u16*)(ws + OFF_W1R);
  u16*   wl_p   = (u16*)(ws + OFF_W1R + 327680);
  u16*   xh_p   = (u16*)(ws + OFF_XH);
  u16*   xl_p   = (u16*)(ws + OFF_XL);
  float* h1p_p  = (float*)(ws + OFF_H1P);
  float* x1_p   = (float*)(ws + OFF_X1);
  u16*   x1b_p  = (u16*)(ws + OFF_X1B);
  u16*   wtqkv  = (u16*)(ws + OFF_WTQKV);
  u16*   g2t_p  = (u16*)(ws + OFF_G2T);
  u16*   wct_p  = (u16*)(ws + OFF_WCT);
  u16*   f1t_p  = (u16*)(ws + OFF_F1T);
  u16*   f2t_p  = (u16*)(ws + OFF_F2T);
  u16*   q_p    = (u16*)(ws + OFF_Q);
  u16*   k_p    = (u16*)(ws + OFF_K);
  u16*   vt_p   = (u16*)(ws + OFF_VT);
  u16*   gmid_p = (u16*)(ws + OFF_GMID);
  float* gates_p= (float*)(ws + OFF_GATES);
  float* ao_p   = (float*)(ws + OFF_AO);
  float* x2_p   = (float*)(ws + OFF_X2);
  u16*   x2b_p  = (u16*)(ws + OFF_X2B);
  float* conv_p = (float*)(ws + OFF_CONV);
  float* x3_p   = (float*)(ws + OFF_X3);
  u16*   x3b_p  = (u16*)(ws + OFF_X3B);
  u16*   fmid_p = (u16*)(ws + OFF_FMID);
  float* fp0_p  = (float*)(ws + OFF_FP0);
  float* fp1_p  = (float*)(ws + OFF_FP1);

  prep_all_kernel<<<3037, 256, 0, stream>>>(wqw, wkw, wvw, g1w, g2w, wcw, f1w, f2w, w1, w2,
                                            ws, w1, wh_p, wl_p, x, xh_p, xl_p);
  conv1g_kernel<<<dim3(128, 1, 4), 256, 0, stream>>>(xh_p, xl_p, wh_p, wl_p, h1p_p);
  conv23_kernel<<<512, 256, 0, stream>>>(h1p_p, c1b, w2r_p, c2b, w3, c3b, x, emb, out1, x1_p, x1b_p);
  {
    // QKV + gates1 merged + fused wavesim (blockIdx.y==0, dispatched first)
    GemmArgs a{}; a.A = x1b_p; a.lda = 512; a.Bt = wtqkv; a.ldb = 512; a.K = 512;
    a.Qo = q_p; a.Ko = k_p; a.Vto = vt_p; a.bq = wqb; a.bk = wkb; a.bv = wvb;
    a.bias = g1b; a.obf = gmid_p; a.ldo = 128;
    a.wmS = out1; a.adjS = out2;
    gemm_k<128,128,4,4,3><<<dim3(64,15), 256, 0, stream>>>(a);
  }
  gates2_kernel<<<128, 256, 0, stream>>>(gmid_p, g2t_p, g2b, gates_p);
  attn_kernel<<<1024, 256, 0, stream>>>(q_p, k_p, vt_p, gates_p, out1, ao_p);
  ln1_kernel<<<2048, 256, 0, stream>>>(ao_p, x1_p, lag, lab, n1g, n1b, x2_p, x2b_p);
  wcg_kernel<<<dim3(64, 8), 256, 0, stream>>>(x2b_p, wct_p, wcb, out1, wwts, conv_p);
  ln2_kernel<<<2048, 256, 0, stream>>>(conv_p, x2_p, lcg, lcb, n2g, n2b, x3_p, x3b_p);
  {
    GemmArgs a{}; a.A = x3b_p; a.lda = 512; a.Bt = f1t_p; a.ldb = 512; a.K = 512;
    a.bias = f1b; a.obf = fmid_p; a.ldo = 2048;
    gemm_k<128,128,4,4,1><<<dim3(64,16), 256, 0, stream>>>(a);
  }
  {
    // ffn2 split-K 2-way: z in {0,1} handles K window [z*1024, z*1024+1024)
    GemmArgs a{}; a.A = fmid_p; a.lda = 2048; a.Bt = f2t_p; a.ldb = 2048; a.K = 1024;
    a.bias = f2b; a.of32 = fp0_p; a.ldo32 = 4194304;
    gemm_k<128,128,4,4,6><<<dim3(64,4,2), 256, 0, stream>>>(a);
  }
  ln3_kernel<<<2048, 256, 0, stream>>>(x3_p, fp0_p, fp1_p, n3g, n3b, out0);

  (void)in_sizes; (void)n_in; (void)out_size; (void)ws_size;
}

// Round 24
// 278.569 us; speedup vs baseline: 1.3088x; 1.3088x over previous
//
#include <hip/hip_runtime.h>

typedef unsigned short u16;
typedef unsigned int u32;
typedef __attribute__((ext_vector_type(8))) short bf16x8;
typedef __attribute__((ext_vector_type(4))) float f32x4;
typedef __attribute__((ext_vector_type(4))) u32 u32x4;

#define DEVI static __device__ __forceinline__

// ---------------- ws layout (bytes), lifetimes verified vs launch order ----------------
constexpr size_t OFF_WTQKV = 0;                       // bf16 [1536][512] (wq^T|wk^T|wv^T)
constexpr size_t OFF_G1T   = 1572864;                 // bf16 [128][512] (contiguous after WTQKV)
constexpr size_t OFF_G2T   = OFF_G1T + 131072;        // bf16 [8][128]
constexpr size_t OFF_WCT   = OFF_G2T + 2048;          // bf16 [3][512][512]
constexpr size_t OFF_F1T   = OFF_WCT + 1572864;       // bf16 [2048][512]
constexpr size_t OFF_F2T   = OFF_F1T + 2097152;       // bf16 [512][2048]
constexpr size_t OFF_W1R   = OFF_F2T + 2097152;       // bf16 wh[64][2560] | wl[64][2560]
constexpr size_t OFF_W2R   = OFF_W1R + 655360;        // f32 [192][64]   ((d*3+k) x c)
constexpr size_t OFF_H1    = OFF_W2R + 49152;         // (slack; GMID aliases here later)
constexpr size_t OFF_GMID  = OFF_H1;                  // bf16 [8192][128]
constexpr size_t OFF_GATES = OFF_H1 + 2097152;        // f32 [8192][8]
constexpr size_t OFF_X1    = OFF_GATES + 262144;      // f32 [8192][512]
constexpr size_t OFF_X3    = OFF_X1;                  // alias: x1 dead after ln1
constexpr size_t OFF_X1B   = OFF_X1 + 16777216;       // bf16 [8192][512]
constexpr size_t OFF_FMID  = OFF_X1B;                 // bf16 [8192][2048]
constexpr size_t OFF_Q     = OFF_X1B + 8388608;       // bf16 [8192][512]
constexpr size_t OFF_H1P   = OFF_Q;                   // f32 [4][8][1024][64] partials
constexpr size_t OFF_K     = OFF_Q + 8388608;         // bf16 [8192][512]
constexpr size_t OFF_XH    = OFF_K;                   // bf16 [8][1028][512] padded x-hi
constexpr size_t OFF_VT    = OFF_K + 8388608;         // bf16 [8][8][64][1024]
constexpr size_t OFF_XL    = OFF_VT + 32768;          // bf16 [8][1028][512] padded x-lo
constexpr size_t OFF_AO    = OFF_VT + 8388608;        // f32 [8192][512]
constexpr size_t OFF_CONV  = OFF_AO;                  // alias
constexpr size_t OFF_FP0   = OFF_AO;                  // alias: ffn2 split-K partial 0
constexpr size_t OFF_X2    = OFF_AO + 16777216;       // f32 [8192][512]
constexpr size_t OFF_FP1   = OFF_X2;                  // alias: ffn2 split-K partial 1
constexpr size_t OFF_X2B   = OFF_X2 + 16777216;       // bf16 [8192][512]
constexpr size_t OFF_X3B   = OFF_X2B;                 // alias
// total ws need = OFF_X2B + 8388608 = 102,811,648 bytes (~98 MB)

DEVI u16 f2bf(float f) {
  u32 u = __builtin_bit_cast(u32, f);
  u32 r = (u + 0x7FFFu + ((u >> 16) & 1u)) >> 16;
  return (u16)r;
}
DEVI float bf2f(u16 h) { u32 u = ((u32)h) << 16; return __builtin_bit_cast(float, u); }

DEVI void load8(const float* __restrict__ p, float o[8]) {
  const float4* q = (const float4*)p;
  float4 a = q[0], b = q[1];
  o[0]=a.x; o[1]=a.y; o[2]=a.z; o[3]=a.w; o[4]=b.x; o[5]=b.y; o[6]=b.z; o[7]=b.w;
}
DEVI void store8(float* __restrict__ p, const float o[8]) {
  float4 a; a.x=o[0]; a.y=o[1]; a.z=o[2]; a.w=o[3];
  float4 b; b.x=o[4]; b.y=o[5]; b.z=o[6]; b.w=o[7];
  float4* q = (float4*)p; q[0]=a; q[1]=b;
}
DEVI void store8bf(u16* __restrict__ p, const float o[8]) {
  u32 w[4];
#pragma unroll
  for (int i=0;i<4;i++) w[i] = (u32)f2bf(o[2*i]) | ((u32)f2bf(o[2*i+1]) << 16);
  u32x4 v; v.x=w[0]; v.y=w[1]; v.z=w[2]; v.w=w[3];
  *(u32x4*)p = v;
}

// async global->LDS, 16 bytes per lane; LDS dest = wave-uniform base + lane*16
DEVI void gl_lds16(const u16* g, u16* l) {
  __builtin_amdgcn_global_load_lds((const __attribute__((address_space(1))) u32*)g,
                                   (__attribute__((address_space(3))) u32*)l, 16, 0, 0);
}

// counted-vmcnt pipeline fences (T4)
#define PIPE_WAIT(N)  asm volatile("s_waitcnt vmcnt(%0)" :: "n"(N) : "memory")
#define PIPE_WAIT0()  asm volatile("s_waitcnt vmcnt(0)" ::: "memory")
#define PIPE_BAR()    do { __builtin_amdgcn_s_barrier(); asm volatile("" ::: "memory"); } while (0)
#define PIPE_BAR_LGKM() do { asm volatile("s_waitcnt lgkmcnt(0)" ::: "memory"); \
                             __builtin_amdgcn_s_barrier(); asm volatile("" ::: "memory"); } while (0)

// ---------------- prep_all: weight transposes + conv1 weight split + x split, one launch ----------------
// blocks [0,917): prep transpose jobs; [917,981): wprep; [981,3037): xsplit
__global__ __launch_bounds__(256) void prep_all_kernel(
    const float* s0, const float* s1, const float* s2, const float* s3, const float* s4,
    const float* s5, const float* s6, const float* s7, const float* s8, const float* s9,
    char* ws,
    const float* __restrict__ w1x, u16* __restrict__ whd, u16* __restrict__ wld,
    const float* __restrict__ x, u16* __restrict__ xh, u16* __restrict__ xl) {
  __shared__ float tile[64][65];
  int blk = blockIdx.x;
  const int tid = threadIdx.x;

  if (blk < 917) {
    // ---- prep transpose job: src [K][N] f32 -> dst [N][K] (bf16 or f32) ----
    const int jsrc[11] = {0,1,2,3,4, 5,5,5, 6,7, 9};
    const int jK[11]   = {512,512,512,512,128, 512,512,512, 512,2048, 64};
    const int jN[11]   = {512,512,512,128,8,   512,512,512, 2048,512, 192};
    const int jSo[11]  = {0,0,0,0,0, 0,262144,524288, 0,0, 0};
    const long long jDo[11] = {
      (long long)OFF_WTQKV, (long long)(OFF_WTQKV+524288), (long long)(OFF_WTQKV+1048576),
      (long long)OFF_G1T, (long long)OFF_G2T,
      (long long)OFF_WCT, (long long)(OFF_WCT+524288), (long long)(OFF_WCT+1048576),
      (long long)OFF_F1T, (long long)OFF_F2T, (long long)OFF_W2R};
    const int jF[11]   = {0,0,0,0,0,0,0,0,0,0,1};

    int j = 0, t = 0;
    for (int i = 0; i < 11; i++) {
      int cnt = ((jK[i] + 63) >> 6) * ((jN[i] + 63) >> 6);
      if (blk < cnt) { j = i; t = blk; break; }
      blk -= cnt;
    }
    int K = jK[j], N = jN[j];
    int ktiles = (K + 63) >> 6;
    int k0 = (t % ktiles) << 6, n0 = (t / ktiles) << 6;
    const float* SS[10] = {s0,s1,s2,s3,s4,s5,s6,s7,s8,s9};
    const float* src = SS[jsrc[j]] + jSo[j];
    for (int i = tid; i < 4096; i += 256) {
      int r = i >> 6, c = i & 63;
      float v = 0.f;
      if (k0 + r < K && n0 + c < N) v = src[(size_t)(k0 + r) * N + n0 + c];
      tile[r][c] = v;
    }
    __syncthreads();
    if (jF[j]) {
      float* dst = (float*)(ws + jDo[j]);
      for (int i = tid; i < 4096; i += 256) {
        int nr = i >> 6, kc = i & 63;
        if (n0 + nr < N && k0 + kc < K) dst[(size_t)(n0 + nr) * K + k0 + kc] = tile[kc][nr];
      }
    } else {
      u16* dst = (u16*)(ws + jDo[j]);
      for (int i = tid; i < 4096; i += 256) {
        int nr = i >> 6, kc = i & 63;
        if (n0 + nr < N && k0 + kc < K) dst[(size_t)(n0 + nr) * K + k0 + kc] = f2bf(tile[kc][nr]);
      }
    }
    return;
  }
  blk -= 917;
  if (blk < 64) {
    // ---- wprep: w1 [64][512][5] -> wh/wl bf16 [64][k*512+d] ----
    int c = blk;
    for (int kk = tid; kk < 2560; kk += 256) {
      int k = kk >> 9, d = kk & 511;
      float v = w1x[(size_t)c * 2560 + d * 5 + k];
      u16 h = f2bf(v);
      whd[(size_t)c * 2560 + kk] = h;
      wld[(size_t)c * 2560 + kk] = f2bf(v - bf2f(h));
    }
    return;
  }
  blk -= 64;
  // ---- xsplit: x [8][1024][512] -> padded bf16 hi/lo [8][1028][512] ----
  {
    int idx = blk * 256 + tid;
    if (idx >= 8 * 1028 * 64) return;
    int r = idx >> 6;
    int col = (idx & 63) * 8;
    int b = r / 1028, rr = r % 1028;
    size_t dof = ((size_t)r) * 512 + col;
    if (rr < 2 || rr >= 1026) {
      u32x4 z; z.x = 0; z.y = 0; z.z = 0; z.w = 0;
      *(u32x4*)&xh[dof] = z;
      *(u32x4*)&xl[dof] = z;
      return;
    }
    const float* src = x + (((size_t)b << 10) + rr - 2) * 512 + col;
    float v[8];
    load8(src, v);
    u32 ph[4], pl[4];
#pragma unroll
    for (int i = 0; i < 4; i++) {
      u16 h0 = f2bf(v[2 * i]),     l0 = f2bf(v[2 * i]     - bf2f(f2bf(v[2 * i])));
      u16 h1 = f2bf(v[2 * i + 1]), l1 = f2bf(v[2 * i + 1] - bf2f(f2bf(v[2 * i + 1])));
      ph[i] = (u32)h0 | ((u32)h1 << 16);
      pl[i] = (u32)l0 | ((u32)l1 << 16);
    }
    u32x4 H; H.x=ph[0]; H.y=ph[1]; H.z=ph[2]; H.w=ph[3];
    u32x4 L; L.x=pl[0]; L.y=pl[1]; L.z=pl[2]; L.w=pl[3];
    *(u32x4*)&xh[dof] = H;
    *(u32x4*)&xl[dof] = L;
  }
}

// ---------------- conv1 v8: MFMA split-bf16 GEMM, 3-buffer depth-2 pipeline, 6 blocks/CU ----------------
__global__ __launch_bounds__(256, 6) void conv1g_kernel(
    const u16* __restrict__ xh, const u16* __restrict__ xl,
    const u16* __restrict__ wh, const u16* __restrict__ wl,
    float* __restrict__ h1p) {
  __shared__ alignas(16) u16 a_s[3][64 * 32];
  __shared__ alignas(16) u16 b_s[3][64 * 32];
  const int tid = threadIdx.x, lane = tid & 63, wid = tid >> 6;
  const int m0 = blockIdx.x * 64;
  const int z = blockIdx.z;
  const int wr = wid >> 1, wc = wid & 1;
  const int mb = wr * 32, nb = wc * 32;
  const int lrow = lane & 15, lk = (lane >> 4) * 8;
  const int lr4 = lane >> 2, lc8 = (lane & 3) * 8;
  const int bb = m0 >> 10, lblk = m0 & 1023;
  const size_t xrow0 = (size_t)bb * 1028;

  auto stage = [&](int buf, int kk) {
    int p = (kk >= 5120) ? 2 : (kk >= 2560) ? 1 : 0;
    int kpp = kk - p * 2560;
    int ktap = kpp >> 9, d0 = kpp & 511;
    const u16* xa = (p == 1) ? xl : xh;
    const u16* wb = (p == 2) ? wl : wh;
    gl_lds16(&xa[(xrow0 + lblk + wid * 16 + lr4 + ktap) * 512 + d0 + lc8],
             &a_s[buf][wid * 512]);
    gl_lds16(&wb[(size_t)(wid * 16 + lr4) * 2560 + kpp + lc8],
             &b_s[buf][wid * 512]);
  };

  f32x4 acc[2][2];
#pragma unroll
  for (int m = 0; m < 2; m++)
#pragma unroll
    for (int n = 0; n < 2; n++) { acc[m][n].x=0.f; acc[m][n].y=0.f; acc[m][n].z=0.f; acc[m][n].w=0.f; }

  const int kz0 = z * 1920, kz1 = kz0 + 1920;
  stage(0, kz0);
  stage(1, kz0 + 32);
  int cur = 0;
  for (int kk = kz0; kk < kz1; kk += 32) {
    if (kk + 64 < kz1) {
      int stg = cur - 1; if (stg < 0) stg = 2;   // (cur+2)%3
      stage(stg, kk + 64);
      PIPE_WAIT(4);
    } else if (kk + 32 < kz1) {
      PIPE_WAIT(2);
    } else {
      PIPE_WAIT0();
    }
    PIPE_BAR();
    bf16x8 af[2], bfr[2];
#pragma unroll
    for (int m = 0; m < 2; m++) af[m]  = *(const bf16x8*)&a_s[cur][(mb + m * 16 + lrow) * 32 + lk];
#pragma unroll
    for (int n = 0; n < 2; n++) bfr[n] = *(const bf16x8*)&b_s[cur][(nb + n * 16 + lrow) * 32 + lk];
#pragma unroll
    for (int m = 0; m < 2; m++)
#pragma unroll
      for (int n = 0; n < 2; n++)
        acc[m][n] = __builtin_amdgcn_mfma_f32_16x16x32_bf16(af[m], bfr[n], acc[m][n], 0, 0, 0);
    PIPE_BAR_LGKM();
    cur = (cur == 2) ? 0 : cur + 1;
  }
  const int r4 = (lane >> 4) * 4;
#pragma unroll
  for (int m = 0; m < 2; m++) {
#pragma unroll
    for (int n = 0; n < 2; n++) {
      const int col = nb + n * 16 + lrow;
#pragma unroll
      for (int j = 0; j < 4; j++) {
        const int row = m0 + mb + m * 16 + r4 + j;
        h1p[(size_t)z * 524288 + (size_t)row * 64 + col] = acc[m][n][j];
      }
    }
  }
}

// ------- conv23 v2: 16-l blocks (512), wave-parallel conv3, vectorized emb-add -------
__global__ __launch_bounds__(256) void conv23_kernel(
    const float* __restrict__ h1p, const float* __restrict__ b1,
    const float* __restrict__ w2r, const float* __restrict__ b2,
    const float* __restrict__ w3, const float* __restrict__ b3,
    const float* __restrict__ x, const float* __restrict__ emb,
    float* __restrict__ wmOut, float* __restrict__ x1, u16* __restrict__ x1b) {
  int seg = blockIdx.x;
  int batch = seg >> 6, l0 = (seg & 63) << 4;
  int tid = threadIdx.x, lane = tid & 63, wave = tid >> 6;
  __shared__ float hs[20][64];
  __shared__ float h2s[18][65];
  __shared__ float w3s[576];
  __shared__ int labS[16];
  for (int i = tid; i < 20 * 64; i += 256) {
    int r = i >> 6, cc = i & 63;
    int lp = l0 - 2 + r;
    float v = 0.f;
    if (lp >= 0 && lp < 1024) {
      size_t base = ((size_t)batch * 1024 + lp) * 64 + cc;
      float s = b1[cc];
#pragma unroll
      for (int q = 0; q < 4; q++) s += h1p[base + (size_t)q * 524288];
      v = fmaxf(s, 0.f);
    }
    hs[r][cc] = v;
  }
  for (int i = tid; i < 576; i += 256) w3s[i] = w3[i];
  __syncthreads();
  {
    int c = lane;
    int r0 = wave * 5;
    float a2[5];
#pragma unroll
    for (int i = 0; i < 5; i++) a2[i] = b2[c];
    for (int dd = 0; dd < 64; dd++) {
      float xv[7];
#pragma unroll
      for (int i = 0; i < 7; i++) xv[i] = (r0 + i < 20) ? hs[r0 + i][dd] : 0.f;
#pragma unroll
      for (int k = 0; k < 3; k++) {
        float wv = w2r[(size_t)(dd * 3 + k) * 64 + c];
#pragma unroll
        for (int i = 0; i < 5; i++) a2[i] += xv[i + k] * wv;
      }
    }
#pragma unroll
    for (int i = 0; i < 5; i++) {
      int hr = r0 + i;
      if (hr < 18) h2s[hr][c] = fmaxf(a2[i], 0.f);
    }
  }
  __syncthreads();
  {
    int li = tid >> 4, g = tid & 15;
    int c0 = g * 4;
    float wp[3];
#pragma unroll
    for (int jw = 0; jw < 3; jw++) {
      float a = 0.f;
#pragma unroll
      for (int k = 0; k < 3; k++)
#pragma unroll
        for (int c = 0; c < 4; c++)
          a += h2s[li + k][c0 + c] * w3s[(jw * 64 + c0 + c) * 3 + k];
      wp[jw] = a;
    }
#pragma unroll
    for (int d = 1; d < 16; d <<= 1) {
#pragma unroll
      for (int jw = 0; jw < 3; jw++) wp[jw] += __shfl_xor(wp[jw], d);
    }
    if (g == 0) {
      float wp0 = wp[0] + b3[0], wp1 = wp[1] + b3[1], wp2 = wp[2] + b3[2];
      float mx = fmaxf(wp0, fmaxf(wp1, wp2));
      float e0 = __expf(wp0 - mx), e1 = __expf(wp1 - mx), e2 = __expf(wp2 - mx);
      float inv = 1.f / (e0 + e1 + e2);
      size_t mo = ((size_t)batch * 1024 + l0 + li) * 3;
      wmOut[mo] = e0 * inv; wmOut[mo + 1] = e1 * inv; wmOut[mo + 2] = e2 * inv;
      int lb = 0; float bv = wp0;
      if (wp1 > bv) { bv = wp1; lb = 1; }
      if (wp2 > bv) { lb = 2; }
      labS[li] = lb;
    }
  }
  __syncthreads();
  for (int i = tid; i < 16 * 128; i += 256) {
    int r = i >> 7, cq = (i & 127) << 2;
    size_t gi = ((size_t)batch * 1024 + l0 + r) * 512 + cq;
    float4 xv = *(const float4*)&x[gi];
    const float* ep = &emb[(size_t)labS[r] * 512 + cq];
    float4 ev = *(const float4*)ep;
    float4 v; v.x = xv.x + ev.x; v.y = xv.y + ev.y; v.z = xv.z + ev.z; v.w = xv.w + ev.w;
    *(float4*)&x1[gi] = v;
    u32 lo = (u32)f2bf(v.x) | ((u32)f2bf(v.y) << 16);
    u32 hi = (u32)f2bf(v.z) | ((u32)f2bf(v.w) << 16);
    *(u32*)&x1b[gi] = lo;
    *(u32*)&x1b[gi + 2] = hi;
  }
}

// ---------------- generic bf16 MFMA GEMM v11: 3-buffer depth-2, wavesim at y==0 ----------------
struct GemmArgs {
  const u16* A; const u16* Bt;
  int lda; int ldb; int K;
  const float* bias;
  u16* obf; int ldo;
  float* of32; int ldo32;
  u16* Qo; u16* Ko; u16* Vto;
  const float* bq; const float* bk; const float* bv;
  const float* wmS; float* adjS;   // fused wavesim (EPI 3, blockIdx.y == 0)
};

// EPI: 1=bias+relu->bf16, 2=bias->f32,
//      3=QKV+gates scatter (V via LDS-transpose); blockIdx.y==0 -> wavesim branch, GEMM n0=(y-1)*BN
//      6=split-K partial f32
template<int BM, int BN, int FM, int FN, int EPI>
__global__ __launch_bounds__(256, 3) void gemm_k(GemmArgs p) {
  __shared__ alignas(16) char smem[49152];   // 3 A-bufs (24KB) + 3 B-bufs (24KB); reused for V-transpose / wavesim
  u16* aS = (u16*)smem;
  u16* bS = aS + 3 * BM * 32;
  const int tid = threadIdx.x;
  const int lane = tid & 63, wid = tid >> 6;

  if constexpr (EPI == 3) {
    if (blockIdx.y == 0) {
      // ---- fused wavesim: adj[b] = wm[b] @ wm[b]^T, 64 blocks (8 b x 8 row-segs of 128) ----
      float* ms = (float*)smem;                       // [1024*3] = 12KB
      const int b = blockIdx.x >> 3;
      const int r0 = (blockIdx.x & 7) << 7;
      for (int i = tid; i < 3072; i += 256) ms[i] = p.wmS[(size_t)b * 3072 + i];
      __syncthreads();
      const int m0q = tid * 4;
      float c0 = ms[(m0q + 0) * 3],     c1 = ms[(m0q + 1) * 3],     c2 = ms[(m0q + 2) * 3],     c3 = ms[(m0q + 3) * 3];
      float d0 = ms[(m0q + 0) * 3 + 1], d1 = ms[(m0q + 1) * 3 + 1], d2 = ms[(m0q + 2) * 3 + 1], d3 = ms[(m0q + 3) * 3 + 1];
      float e0 = ms[(m0q + 0) * 3 + 2], e1 = ms[(m0q + 1) * 3 + 2], e2 = ms[(m0q + 2) * 3 + 2], e3 = ms[(m0q + 3) * 3 + 2];
      for (int r = 0; r < 128; r++) {
        float a0 = ms[(r0 + r) * 3], a1 = ms[(r0 + r) * 3 + 1], a2 = ms[(r0 + r) * 3 + 2];
        f32x4 v;
        v.x = a0 * c0 + a1 * d0 + a2 * e0;
        v.y = a0 * c1 + a1 * d1 + a2 * e1;
        v.z = a0 * c2 + a1 * d2 + a2 * e2;
        v.w = a0 * c3 + a1 * d3 + a2 * e3;
        __builtin_nontemporal_store(v, (f32x4*)&p.adjS[((size_t)b * 1024 + r0 + r) * 1024 + m0q]);
      }
      return;
    }
  }

  const int m0 = blockIdx.x * BM;
  const int n0 = (EPI == 3) ? (blockIdx.y - 1) * BN : blockIdx.y * BN;
  const int koff = (EPI == 6) ? blockIdx.z * p.K : 0;
  const int wr = wid >> 1, wc = wid & 1;
  const int mb = wr * (FM * 16), nb = wc * (FN * 16);
  const int lrow = lane & 15, lk = (lane >> 4) * 8;
  constexpr int CPW_A = BM / 64;
  constexpr int CPW_B = BN / 64;
  constexpr int NL = CPW_A + CPW_B;
  const int lr4 = lane >> 2, lc8 = (lane & 3) * 8;

  auto stage = [&](int buf, int k0) {
#pragma unroll
    for (int j = 0; j < CPW_A; j++) {
      int chunk = wid * CPW_A + j;
      gl_lds16(&p.A[(size_t)(m0 + chunk * 16 + lr4) * p.lda + koff + k0 + lc8],
               &aS[buf * BM * 32 + chunk * 512]);
    }
#pragma unroll
    for (int j = 0; j < CPW_B; j++) {
      int chunk = wid * CPW_B + j;
      gl_lds16(&p.Bt[(size_t)(n0 + chunk * 16 + lr4) * p.ldb + koff + k0 + lc8],
               &bS[buf * BN * 32 + chunk * 512]);
    }
  };

  f32x4 acc[FM][FN];
#pragma unroll
  for (int m = 0; m < FM; m++)
#pragma unroll
    for (int n = 0; n < FN; n++) { acc[m][n].x=0.f; acc[m][n].y=0.f; acc[m][n].z=0.f; acc[m][n].w=0.f; }

  stage(0, 0);
  stage(1, 32);
  int cur = 0;
  for (int k0 = 0; k0 < p.K; k0 += 32) {
    if (k0 + 64 < p.K) {
      int stg = cur - 1; if (stg < 0) stg = 2;   // (cur+2)%3
      stage(stg, k0 + 64);
      PIPE_WAIT(2 * NL);
    } else if (k0 + 32 < p.K) {
      PIPE_WAIT(NL);
    } else {
      PIPE_WAIT0();
    }
    PIPE_BAR();
    bf16x8 af[FM], bfr[FN];
#pragma unroll
    for (int m = 0; m < FM; m++)
      af[m] = *(const bf16x8*)&aS[cur * BM * 32 + (mb + m * 16 + lrow) * 32 + lk];
#pragma unroll
    for (int n = 0; n < FN; n++)
      bfr[n] = *(const bf16x8*)&bS[cur * BN * 32 + (nb + n * 16 + lrow) * 32 + lk];
#pragma unroll
    for (int m = 0; m < FM; m++)
#pragma unroll
      for (int n = 0; n < FN; n++)
        acc[m][n] = __builtin_amdgcn_mfma_f32_16x16x32_bf16(af[m], bfr[n], acc[m][n], 0, 0, 0);
    PIPE_BAR_LGKM();
    cur = (cur == 2) ? 0 : cur + 1;
  }
  const int r4 = (lane >> 4) * 4;

  if constexpr (EPI == 3) {
    if (n0 >= 1024 && n0 < 1536) {
      // ---- V-region block: LDS-transpose + coalesced bf16 stores ----
      float* ts = (float*)smem;              // [64 cols][128 rows], chunk-XOR swizzled (32KB <= 48KB)
      const int bb = m0 >> 10, lblk = m0 & 1023;
#pragma unroll
      for (int H = 0; H < 2; H++) {
        __syncthreads();
        if (wc == H) {
#pragma unroll
          for (int m = 0; m < FM; m++) {
#pragma unroll
            for (int n = 0; n < FN; n++) {
              const int c = n * 16 + lrow;
              const int cc = (n0 - 1024) + H * 64 + c;
              const float bvv = p.bv[cc];
#pragma unroll
              for (int j = 0; j < 4; j++) {
                const int r = mb + m * 16 + r4 + j;
                ts[c * 128 + (r ^ ((c & 3) << 2))] = acc[m][n][j] + bvv;
              }
            }
          }
        }
        __syncthreads();
        const int c = tid >> 2, seg = tid & 3;
        const int cc = (n0 - 1024) + H * 64 + c;
        const int hh = cc >> 6, dd = cc & 63;
        u16* dst = &p.Vto[((((size_t)bb * 8 + hh) * 64 + dd) << 10) + lblk + seg * 32];
        u32 pk[16];
#pragma unroll
        for (int j = 0; j < 8; j++) {
          const int chunk = seg * 8 + j;
          f32x4 v4 = *(const f32x4*)&ts[c * 128 + ((chunk ^ (c & 3)) << 2)];
          pk[2 * j + 0] = (u32)f2bf(v4.x) | ((u32)f2bf(v4.y) << 16);
          pk[2 * j + 1] = (u32)f2bf(v4.z) | ((u32)f2bf(v4.w) << 16);
        }
#pragma unroll
        for (int q = 0; q < 4; q++) {
          u32x4 sv; sv.x = pk[4 * q]; sv.y = pk[4 * q + 1]; sv.z = pk[4 * q + 2]; sv.w = pk[4 * q + 3];
          *(u32x4*)&dst[q * 8] = sv;
        }
      }
      return;
    }
  }

#pragma unroll
  for (int m = 0; m < FM; m++) {
#pragma unroll
    for (int n = 0; n < FN; n++) {
      const int col = n0 + nb + n * 16 + lrow;
#pragma unroll
      for (int j = 0; j < 4; j++) {
        const int row = m0 + mb + m * 16 + r4 + j;
        float v = acc[m][n][j];
        if constexpr (EPI == 1) {
          v += p.bias[col];
          v = fmaxf(v, 0.f);
          p.obf[(size_t)row * p.ldo + col] = f2bf(v);
        } else if constexpr (EPI == 2) {
          v += p.bias[col];
          p.of32[(size_t)row * p.ldo32 + col] = v;
        } else if constexpr (EPI == 3) {
          if (col < 512) {
            v += p.bq[col];
            p.Qo[(size_t)row * 512 + col] = f2bf(v);
          } else if (col < 1024) {
            int cc = col - 512;
            v += p.bk[cc];
            p.Ko[(size_t)row * 512 + cc] = f2bf(v);
          } else if (col >= 1536) {
            int cc = col - 1536;
            v += p.bias[cc];
            v = fmaxf(v, 0.f);
            p.obf[(size_t)row * 128 + cc] = f2bf(v);
          }
        } else if constexpr (EPI == 6) {
          if (blockIdx.z == 0) v += p.bias[col];
          p.of32[(size_t)blockIdx.z * p.ldo32 + (size_t)row * 512 + col] = v;
        }
      }
    }
  }
}

// ---------------- fused wc GEMM v5: 2-buffer counted-vmcnt pipeline (unhinted) ----------------
__global__ __launch_bounds__(256) void wcg_kernel(
    const u16* __restrict__ A, const u16* __restrict__ Wct,
    const float* __restrict__ wcb, const float* __restrict__ wmask,
    const float* __restrict__ wwts, float* __restrict__ out) {
  __shared__ alignas(16) u16 a_s[2][128 * 32];
  __shared__ alignas(16) u16 b_s[2][3 * 64 * 32];
  const int tid = threadIdx.x, lane = tid & 63, wid = tid >> 6;
  const int m0 = blockIdx.x * 128, n0 = blockIdx.y * 64;
  const int wr = wid >> 1, wc = wid & 1;
  const int mb = wr * 64, nb = wc * 32;
  const int lrow = lane & 15, lk = (lane >> 4) * 8;
  const int lr4 = lane >> 2, lc8 = (lane & 3) * 8;

  auto stage = [&](int buf, int k0) {
#pragma unroll
    for (int t = 0; t < 2; t++) {
      int ch = wid * 2 + t;
      gl_lds16(&A[(size_t)(m0 + ch * 16 + lr4) * 512 + k0 + lc8], &a_s[buf][ch * 512]);
    }
#pragma unroll
    for (int t = 0; t < 3; t++) {
      int ch = wid * 3 + t;
      int wI = ch >> 2, sub = ch & 3;
      gl_lds16(&Wct[(size_t)wI * 262144 + (size_t)(n0 + sub * 16 + lr4) * 512 + k0 + lc8],
               &b_s[buf][ch * 512]);
    }
  };

  f32x4 acc[4][2][3];
#pragma unroll
  for (int m = 0; m < 4; m++)
#pragma unroll
    for (int n = 0; n < 2; n++)
#pragma unroll
      for (int w = 0; w < 3; w++) { acc[m][n][w].x=0.f; acc[m][n][w].y=0.f; acc[m][n][w].z=0.f; acc[m][n][w].w=0.f; }

  stage(0, 0);
  int cur = 0;
  for (int k0 = 0; k0 < 512; k0 += 32) {
    if (k0 + 32 < 512) {
      stage(cur ^ 1, k0 + 32);
      PIPE_WAIT(5);
    } else {
      PIPE_WAIT0();
    }
    PIPE_BAR();
    bf16x8 af[4], bfr[3][2];
#pragma unroll
    for (int m = 0; m < 4; m++) af[m] = *(const bf16x8*)&a_s[cur][(mb + m * 16 + lrow) * 32 + lk];
#pragma unroll
    for (int w = 0; w < 3; w++)
#pragma unroll
      for (int n = 0; n < 2; n++)
        bfr[w][n] = *(const bf16x8*)&b_s[cur][(w * 64 + nb + n * 16 + lrow) * 32 + lk];
#pragma unroll
    for (int m = 0; m < 4; m++)
#pragma unroll
      for (int n = 0; n < 2; n++)
#pragma unroll
        for (int w = 0; w < 3; w++)
          acc[m][n][w] = __builtin_amdgcn_mfma_f32_16x16x32_bf16(af[m], bfr[w][n], acc[m][n][w], 0, 0, 0);
    PIPE_BAR_LGKM();
    cur ^= 1;
  }
  const float w0 = wwts[0], w1 = wwts[1], w2 = wwts[2];
  const int r4 = (lane >> 4) * 4;
#pragma unroll
  for (int m = 0; m < 4; m++) {
#pragma unroll
    for (int j = 0; j < 4; j++) {
      const int row = m0 + mb + m * 16 + r4 + j;
      float c0 = wmask[(size_t)row * 3 + 0] * w0;
      float c1 = wmask[(size_t)row * 3 + 1] * w1;
      float c2 = wmask[(size_t)row * 3 + 2] * w2;
#pragma unroll
      for (int n = 0; n < 2; n++) {
        const int col = n0 + nb + n * 16 + lrow;
        float v = c0 * (acc[m][n][0][j] + wcb[col])
                + c1 * (acc[m][n][1][j] + wcb[512 + col])
                + c2 * (acc[m][n][2][j] + wcb[1024 + col]);
        out[(size_t)row * 512 + col] = v;
      }
    }
  }
}

// ---------------- gates stage 2: sigmoid(mid @ g2 + b), N=8 ----------------
__global__ __launch_bounds__(256) void gates2_kernel(const u16* __restrict__ gmid,
    const u16* __restrict__ g2t, const float* __restrict__ g2b, float* __restrict__ gates) {
  int r0 = blockIdx.x * 64;
  __shared__ u16 ms[64][136];
  __shared__ u16 gs[8][136];
  __shared__ float gb[8];
  int tid = threadIdx.x;
  for (int i = tid; i < 1024; i += 256) {
    int r = i >> 4, ch = (i & 15) * 8;
    *(bf16x8*)&ms[r][ch] = *(const bf16x8*)&gmid[(size_t)(r0 + r) * 128 + ch];
  }
  if (tid < 128) {
    int r = tid >> 4, ch = (tid & 15) * 8;
    *(bf16x8*)&gs[r][ch] = *(const bf16x8*)&g2t[(size_t)r * 128 + ch];
  }
  if (tid < 8) gb[tid] = g2b[tid];
  __syncthreads();
  for (int o = tid; o < 512; o += 256) {
    int r = o >> 3, hh = o & 7;
    float a = gb[hh];
    for (int k = 0; k < 128; k++) a += bf2f(ms[r][k]) * bf2f(gs[hh][k]);
    gates[(size_t)(r0 + r) * 8 + hh] = 1.f / (1.f + __expf(-a));
  }
}

// ---------------- fused flash attention v4: single-buffer, 4 blocks/CU hint ----------------
__global__ __launch_bounds__(256, 4) void attn_kernel(
    const u16* __restrict__ Qb, const u16* __restrict__ Kb, const u16* __restrict__ Vt,
    const float* __restrict__ gates, const float* __restrict__ wm, float* __restrict__ ao) {
  const int g = blockIdx.x & 63, qt = blockIdx.x >> 6;
  const int b = g >> 3, h = g & 7, q0 = qt << 6;
  const int tid = threadIdx.x, lane = tid & 63, w = tid >> 6;
  __shared__ alignas(16) u16 k_s[64 * 64];
  __shared__ alignas(16) u16 v_s[64 * 64];
  __shared__ u16 p_s[4][16][72];
  __shared__ float gat[64];
  __shared__ float wmk[64][4];
  const int lrow = lane & 15, lq = lane >> 4, lk = lq * 8;
  const int qrb = q0 + w * 16;
  const int sr_ = lane >> 3, sc_ = lane & 7;
  bf16x8 qf[2];
#pragma unroll
  for (int ks = 0; ks < 2; ks++)
    qf[ks] = *(const bf16x8*)&Qb[((size_t)(b * 1024 + qrb + lrow)) * 512 + h * 64 + ks * 32 + lk];
  float wq_[4][3];
#pragma unroll
  for (int j = 0; j < 4; j++) {
    int qr = qrb + lq * 4 + j;
#pragma unroll
    for (int t = 0; t < 3; t++) wq_[j][t] = wm[((size_t)b * 1024 + qr) * 3 + t];
  }
  float lsum[4];
  f32x4 oacc[4];
#pragma unroll
  for (int j = 0; j < 4; j++) lsum[j] = 0.f;
#pragma unroll
  for (int n = 0; n < 4; n++) { oacc[n].x=0.f; oacc[n].y=0.f; oacc[n].z=0.f; oacc[n].w=0.f; }

  const u16* Kbase = Kb + ((size_t)b * 1024) * 512 + h * 64;
  const u16* Vbase = Vt + ((size_t)(b * 8 + h)) * 64 * 1024;

  for (int kt = 0; kt < 16; kt++) {
    int k0 = kt * 64;
    __syncthreads();
#pragma unroll
    for (int t = 0; t < 2; t++) {
      int ch = (w << 1) | t;
      int r = (ch << 3) | sr_;
      int srcc = ((sc_ ^ (r & 7)) << 3);
      gl_lds16(&Kbase[(size_t)(k0 + r) * 512 + srcc], &k_s[ch << 9]);
      gl_lds16(&Vbase[(size_t)r * 1024 + k0 + srcc], &v_s[ch << 9]);
    }
    if (tid < 64) {
      gat[tid] = gates[((size_t)b * 1024 + k0 + tid) * 8 + h];
#pragma unroll
      for (int t = 0; t < 3; t++) wmk[tid][t] = wm[((size_t)b * 1024 + k0 + tid) * 3 + t];
    }
    __syncthreads();
    f32x4 s[4];
#pragma unroll
    for (int n = 0; n < 4; n++) { s[n].x=0.f; s[n].y=0.f; s[n].z=0.f; s[n].w=0.f; }
#pragma unroll
    for (int ks = 0; ks < 2; ks++) {
      bf16x8 kf[4];
#pragma unroll
      for (int n = 0; n < 4; n++) {
        int kr = n * 16 + lrow;
        kf[n] = *(const bf16x8*)&k_s[kr * 64 + ((((ks << 2) | lq) ^ (kr & 7)) << 3)];
      }
#pragma unroll
      for (int n = 0; n < 4; n++)
        s[n] = __builtin_amdgcn_mfma_f32_16x16x32_bf16(qf[ks], kf[n], s[n], 0, 0, 0);
    }
    float pv[4][4];
#pragma unroll
    for (int n = 0; n < 4; n++) {
      int cl = n * 16 + lrow;
      float gg = gat[cl];
      float w0 = wmk[cl][0], w1 = wmk[cl][1], w2 = wmk[cl][2];
#pragma unroll
      for (int j = 0; j < 4; j++) {
        float wsv = wq_[j][0] * w0 + wq_[j][1] * w1 + wq_[j][2] * w2;
        float sv = s[n][j] * 0.125f;
        float e = __expf(sv * (gg + wsv) + wsv);
        pv[n][j] = e;
        lsum[j] += e;
      }
    }
#pragma unroll
    for (int n = 0; n < 4; n++)
#pragma unroll
      for (int j = 0; j < 4; j++)
        p_s[w][lq * 4 + j][n * 16 + lrow] = f2bf(pv[n][j]);
#pragma unroll
    for (int ks = 0; ks < 2; ks++) {
      bf16x8 pa, vb[4];
      pa = *(const bf16x8*)&p_s[w][lrow][ks * 32 + lk];
#pragma unroll
      for (int n = 0; n < 4; n++) {
        int vr = n * 16 + lrow;
        vb[n] = *(const bf16x8*)&v_s[vr * 64 + ((((ks << 2) | lq) ^ (vr & 7)) << 3)];
      }
#pragma unroll
      for (int n = 0; n < 4; n++)
        oacc[n] = __builtin_amdgcn_mfma_f32_16x16x32_bf16(pa, vb[n], oacc[n], 0, 0, 0);
    }
  }
  float rinv[4];
#pragma unroll
  for (int j = 0; j < 4; j++) {
    float s = lsum[j];
#pragma unroll
    for (int d = 1; d < 16; d <<= 1) s += __shfl_xor(s, d);
    rinv[j] = 1.f / s;
  }
#pragma unroll
  for (int n = 0; n < 4; n++) {
    int col = h * 64 + n * 16 + lrow;
#pragma unroll
    for (int j = 0; j < 4; j++) {
      int row = b * 1024 + qrb + lq * 4 + j;
      ao[(size_t)row * 512 + col] = oacc[n][j] * rinv[j];
    }
  }
}

// ---------------- LayerNorm helpers & fused double-LN kernels ----------------
DEVI void ln512(const float u[8], const float* __restrict__ g, const float* __restrict__ b,
                int lane, float out[8]) {
  float s = 0.f;
#pragma unroll
  for (int i = 0; i < 8; i++) s += u[i];
#pragma unroll
  for (int m = 1; m < 64; m <<= 1) s += __shfl_xor(s, m);
  float mean = s * (1.f / 512.f);
  float d[8], q = 0.f;
#pragma unroll
  for (int i = 0; i < 8; i++) { d[i] = u[i] - mean; q += d[i] * d[i]; }
#pragma unroll
  for (int m = 1; m < 64; m <<= 1) q += __shfl_xor(q, m);
  float inv = rsqrtf(q * (1.f / 512.f) + 1e-5f);
  int base = lane * 8;
#pragma unroll
  for (int i = 0; i < 8; i++) out[i] = d[i] * inv * g[base + i] + b[base + i];
}

__global__ __launch_bounds__(256) void ln1_kernel(
    const float* __restrict__ ao, const float* __restrict__ x1,
    const float* __restrict__ ga, const float* __restrict__ gb,
    const float* __restrict__ n1g, const float* __restrict__ n1b,
    float* __restrict__ x2, u16* __restrict__ x2b) {
  int row = blockIdx.x * 4 + (threadIdx.x >> 6);
  int lane = threadIdx.x & 63;
  size_t base = (size_t)row * 512 + lane * 8;
  float av[8], xv[8], u[8], t[8];
  load8(ao + base, av);
  load8(x1 + base, xv);
#pragma unroll
  for (int i = 0; i < 8; i++) u[i] = av[i] + xv[i];
  ln512(u, ga, gb, lane, t);
#pragma unroll
  for (int i = 0; i < 8; i++) u[i] = xv[i] + t[i];
  ln512(u, n1g, n1b, lane, t);
  store8(x2 + base, t);
  store8bf(x2b + base, t);
}

__global__ __launch_bounds__(256) void ln2_kernel(
    const float* __restrict__ co, const float* __restrict__ x2,
    const float* __restrict__ gc, const float* __restrict__ bc,
    const float* __restrict__ n2g, const float* __restrict__ n2b,
    float* __restrict__ x3, u16* __restrict__ x3b) {
  int row = blockIdx.x * 4 + (threadIdx.x >> 6);
  int lane = threadIdx.x & 63;
  size_t base = (size_t)row * 512 + lane * 8;
  float av[8], xv[8], u[8], t[8];
  load8(co + base, av);
#pragma unroll
  for (int i = 0; i < 8; i++) u[i] = fmaxf(av[i], 0.f);
  ln512(u, gc, bc, lane, t);
  load8(x2 + base, xv);
#pragma unroll
  for (int i = 0; i < 8; i++) u[i] = xv[i] + t[i];
  ln512(u, n2g, n2b, lane, t);
  store8(x3 + base, t);
  store8bf(x3b + base, t);
}

// ln3 v2: sums the two ffn2 split-K partials (bias already in p0)
__global__ __launch_bounds__(256) void ln3_kernel(
    const float* __restrict__ x3, const float* __restrict__ p0, const float* __restrict__ p1,
    const float* __restrict__ n3g, const float* __restrict__ n3b,
    float* __restrict__ out0) {
  int row = blockIdx.x * 4 + (threadIdx.x >> 6);
  int lane = threadIdx.x & 63;
  size_t base = (size_t)row * 512 + lane * 8;
  float a0[8], a1[8], xv[8], u[8], t[8];
  load8(x3 + base, xv);
  load8(p0 + base, a0);
  load8(p1 + base, a1);
#pragma unroll
  for (int i = 0; i < 8; i++) u[i] = xv[i] + a0[i] + a1[i];
  ln512(u, n3g, n3b, lane, t);
  store8(out0 + base, t);
}

// ---------------- host launch ----------------
extern "C" void kernel_launch(void* const* d_in, const int* in_sizes, int n_in,
                              void* d_out, int out_size, void* d_ws, size_t ws_size,
                              hipStream_t stream) {
  const float* x    = (const float*)d_in[0];
  const float* w1   = (const float*)d_in[1];
  const float* c1b  = (const float*)d_in[2];
  const float* w2   = (const float*)d_in[3];
  const float* c2b  = (const float*)d_in[4];
  const float* w3   = (const float*)d_in[5];
  const float* c3b  = (const float*)d_in[6];
  const float* emb  = (const float*)d_in[7];
  const float* wqw  = (const float*)d_in[8];
  const float* wqb  = (const float*)d_in[9];
  const float* wkw  = (const float*)d_in[10];
  const float* wkb  = (const float*)d_in[11];
  const float* wvw  = (const float*)d_in[12];
  const float* wvb  = (const float*)d_in[13];
  const float* g1w  = (const float*)d_in[14];
  const float* g1b  = (const float*)d_in[15];
  const float* g2w  = (const float*)d_in[16];
  const float* g2b  = (const float*)d_in[17];
  const float* lag  = (const float*)d_in[18];
  const float* lab  = (const float*)d_in[19];
  const float* n1g  = (const float*)d_in[20];
  const float* n1b  = (const float*)d_in[21];
  const float* lcg  = (const float*)d_in[22];
  const float* lcb  = (const float*)d_in[23];
  const float* n2g  = (const float*)d_in[24];
  const float* n2b  = (const float*)d_in[25];
  const float* n3g  = (const float*)d_in[26];
  const float* n3b  = (const float*)d_in[27];
  const float* wcw  = (const float*)d_in[28];
  const float* wcb  = (const float*)d_in[29];
  const float* wwts = (const float*)d_in[30];
  const float* f1w  = (const float*)d_in[31];
  const float* f1b  = (const float*)d_in[32];
  const float* f2w  = (const float*)d_in[33];
  const float* f2b  = (const float*)d_in[34];

  char* ws = (char*)d_ws;
  float* out0 = (float*)d_out;
  float* out1 = out0 + 4194304;   // wave_mask [8,1024,3]
  float* out2 = out1 + 24576;     // subgraph_adj [8,1024,1024]

  float* w2r_p  = (float*)(ws + OFF_W2R);
  u16*   wh_p   = (u16*)(ws + OFF_W1R);
  u16*   wl_p   = (u16*)(ws + OFF_W1R + 327680);
  u16*   xh_p   = (u16*)(ws + OFF_XH);
  u16*   xl_p   = (u16*)(ws + OFF_XL);
  float* h1p_p  = (float*)(ws + OFF_H1P);
  float* x1_p   = (float*)(ws + OFF_X1);
  u16*   x1b_p  = (u16*)(ws + OFF_X1B);
  u16*   wtqkv  = (u16*)(ws + OFF_WTQKV);
  u16*   g2t_p  = (u16*)(ws + OFF_G2T);
  u16*   wct_p  = (u16*)(ws + OFF_WCT);
  u16*   f1t_p  = (u16*)(ws + OFF_F1T);
  u16*   f2t_p  = (u16*)(ws + OFF_F2T);
  u16*   q_p    = (u16*)(ws + OFF_Q);
  u16*   k_p    = (u16*)(ws + OFF_K);
  u16*   vt_p   = (u16*)(ws + OFF_VT);
  u16*   gmid_p = (u16*)(ws + OFF_GMID);
  float* gates_p= (float*)(ws + OFF_GATES);
  float* ao_p   = (float*)(ws + OFF_AO);
  float* x2_p   = (float*)(ws + OFF_X2);
  u16*   x2b_p  = (u16*)(ws + OFF_X2B);
  float* conv_p = (float*)(ws + OFF_CONV);
  float* x3_p   = (float*)(ws + OFF_X3);
  u16*   x3b_p  = (u16*)(ws + OFF_X3B);
  u16*   fmid_p = (u16*)(ws + OFF_FMID);
  float* fp0_p  = (float*)(ws + OFF_FP0);
  float* fp1_p  = (float*)(ws + OFF_FP1);

  prep_all_kernel<<<3037, 256, 0, stream>>>(wqw, wkw, wvw, g1w, g2w, wcw, f1w, f2w, w1, w2,
                                            ws, w1, wh_p, wl_p, x, xh_p, xl_p);
  conv1g_kernel<<<dim3(128, 1, 4), 256, 0, stream>>>(xh_p, xl_p, wh_p, wl_p, h1p_p);
  conv23_kernel<<<512, 256, 0, stream>>>(h1p_p, c1b, w2r_p, c2b, w3, c3b, x, emb, out1, x1_p, x1b_p);
  {
    // QKV + gates1 merged + fused wavesim (blockIdx.y==0, dispatched first)
    GemmArgs a{}; a.A = x1b_p; a.lda = 512; a.Bt = wtqkv; a.ldb = 512; a.K = 512;
    a.Qo = q_p; a.Ko = k_p; a.Vto = vt_p; a.bq = wqb; a.bk = wkb; a.bv = wvb;
    a.bias = g1b; a.obf = gmid_p; a.ldo = 128;
    a.wmS = out1; a.adjS = out2;
    gemm_k<128,128,4,4,3><<<dim3(64,15), 256, 0, stream>>>(a);
  }
  gates2_kernel<<<128, 256, 0, stream>>>(gmid_p, g2t_p, g2b, gates_p);
  attn_kernel<<<1024, 256, 0, stream>>>(q_p, k_p, vt_p, gates_p, out1, ao_p);
  ln1_kernel<<<2048, 256, 0, stream>>>(ao_p, x1_p, lag, lab, n1g, n1b, x2_p, x2b_p);
  wcg_kernel<<<dim3(64, 8), 256, 0, stream>>>(x2b_p, wct_p, wcb, out1, wwts, conv_p);
  ln2_kernel<<<2048, 256, 0, stream>>>(conv_p, x2_p, lcg, lcb, n2g, n2b, x3_p, x3b_p);
  {
    GemmArgs a{}; a.A = x3b_p; a.lda = 512; a.Bt = f1t_p; a.ldb = 512; a.K = 512;
    a.bias = f1b; a.obf = fmid_p; a.ldo = 2048;
    gemm_k<128,128,4,4,1><<<dim3(64,16), 256, 0, stream>>>(a);
  }
  {
    // ffn2 split-K 2-way: z in {0,1} handles K window [z*1024, z*1024+1024)
    GemmArgs a{}; a.A = fmid_p; a.lda = 2048; a.Bt = f2t_p; a.ldb = 2048; a.K = 1024;
    a.bias = f2b; a.of32 = fp0_p; a.ldo32 = 4194304;
    gemm_k<128,128,4,4,6><<<dim3(64,4,2), 256, 0, stream>>>(a);
  }
  ln3_kernel<<<2048, 256, 0, stream>>>(x3_p, fp0_p, fp1_p, n3g, n3b, out0);

  (void)in_sizes; (void)n_in; (void)out_size; (void)ws_size;
}

// Round 25
// 276.881 us; speedup vs baseline: 1.3168x; 1.0061x over previous
//
#include <hip/hip_runtime.h>

typedef unsigned short u16;
typedef unsigned int u32;
typedef __attribute__((ext_vector_type(8))) short bf16x8;
typedef __attribute__((ext_vector_type(4))) float f32x4;
typedef __attribute__((ext_vector_type(4))) u32 u32x4;

#define DEVI static __device__ __forceinline__

// ---------------- ws layout (bytes), lifetimes verified vs launch order ----------------
constexpr size_t OFF_WTQKV = 0;                       // bf16 [1536][512] (wq^T|wk^T|wv^T)
constexpr size_t OFF_G1T   = 1572864;                 // bf16 [128][512] (contiguous after WTQKV)
constexpr size_t OFF_G2T   = OFF_G1T + 131072;        // bf16 [8][128]
constexpr size_t OFF_WCT   = OFF_G2T + 2048;          // bf16 [3][512][512]
constexpr size_t OFF_F1T   = OFF_WCT + 1572864;       // bf16 [2048][512]
constexpr size_t OFF_F2T   = OFF_F1T + 2097152;       // bf16 [512][2048]
constexpr size_t OFF_W1R   = OFF_F2T + 2097152;       // bf16 wh[64][2560] | wl[64][2560]
constexpr size_t OFF_W2R   = OFF_W1R + 655360;        // f32 [192][64]   ((d*3+k) x c)
constexpr size_t OFF_H1    = OFF_W2R + 49152;         // (slack; GMID aliases here later)
constexpr size_t OFF_GMID  = OFF_H1;                  // bf16 [8192][128]
constexpr size_t OFF_GATES = OFF_H1 + 2097152;        // f32 [8192][8]
constexpr size_t OFF_X1    = OFF_GATES + 262144;      // f32 [8192][512]
constexpr size_t OFF_X3    = OFF_X1;                  // alias: x1 dead after ln1
constexpr size_t OFF_X1B   = OFF_X1 + 16777216;       // bf16 [8192][512]
constexpr size_t OFF_FMID  = OFF_X1B;                 // bf16 [8192][2048]
constexpr size_t OFF_Q     = OFF_X1B + 8388608;       // bf16 [8192][512]
constexpr size_t OFF_H1P   = OFF_Q;                   // f32 [4][8][1024][64] partials
constexpr size_t OFF_K     = OFF_Q + 8388608;         // bf16 [8192][512]
constexpr size_t OFF_XH    = OFF_K;                   // bf16 [8][1028][512] padded x-hi
constexpr size_t OFF_VT    = OFF_K + 8388608;         // bf16 [8][8][64][1024]
constexpr size_t OFF_XL    = OFF_VT + 32768;          // bf16 [8][1028][512] padded x-lo
constexpr size_t OFF_AO    = OFF_VT + 8388608;        // f32 [8192][512]
constexpr size_t OFF_CONV  = OFF_AO;                  // alias
constexpr size_t OFF_FP0   = OFF_AO;                  // alias: ffn2 split-K partial 0
constexpr size_t OFF_X2    = OFF_AO + 16777216;       // f32 [8192][512]
constexpr size_t OFF_FP1   = OFF_X2;                  // alias: ffn2 split-K partial 1
constexpr size_t OFF_X2B   = OFF_X2 + 16777216;       // bf16 [8192][512]
constexpr size_t OFF_X3B   = OFF_X2B;                 // alias
// total ws need = OFF_X2B + 8388608 = 102,811,648 bytes (~98 MB)

DEVI u16 f2bf(float f) {
  u32 u = __builtin_bit_cast(u32, f);
  u32 r = (u + 0x7FFFu + ((u >> 16) & 1u)) >> 16;
  return (u16)r;
}
DEVI float bf2f(u16 h) { u32 u = ((u32)h) << 16; return __builtin_bit_cast(float, u); }

DEVI void load8(const float* __restrict__ p, float o[8]) {
  const float4* q = (const float4*)p;
  float4 a = q[0], b = q[1];
  o[0]=a.x; o[1]=a.y; o[2]=a.z; o[3]=a.w; o[4]=b.x; o[5]=b.y; o[6]=b.z; o[7]=b.w;
}
DEVI void store8(float* __restrict__ p, const float o[8]) {
  float4 a; a.x=o[0]; a.y=o[1]; a.z=o[2]; a.w=o[3];
  float4 b; b.x=o[4]; b.y=o[5]; b.z=o[6]; b.w=o[7];
  float4* q = (float4*)p; q[0]=a; q[1]=b;
}
DEVI void store8bf(u16* __restrict__ p, const float o[8]) {
  u32 w[4];
#pragma unroll
  for (int i=0;i<4;i++) w[i] = (u32)f2bf(o[2*i]) | ((u32)f2bf(o[2*i+1]) << 16);
  u32x4 v; v.x=w[0]; v.y=w[1]; v.z=w[2]; v.w=w[3];
  *(u32x4*)p = v;
}

// async global->LDS, 16 bytes per lane; LDS dest = wave-uniform base + lane*16
DEVI void gl_lds16(const u16* g, u16* l) {
  __builtin_amdgcn_global_load_lds((const __attribute__((address_space(1))) u32*)g,
                                   (__attribute__((address_space(3))) u32*)l, 16, 0, 0);
}

// counted-vmcnt pipeline fences (T4)
#define PIPE_WAIT(N)  asm volatile("s_waitcnt vmcnt(%0)" :: "n"(N) : "memory")
#define PIPE_WAIT0()  asm volatile("s_waitcnt vmcnt(0)" ::: "memory")
#define PIPE_BAR()    do { __builtin_amdgcn_s_barrier(); asm volatile("" ::: "memory"); } while (0)
#define PIPE_BAR_LGKM() do { asm volatile("s_waitcnt lgkmcnt(0)" ::: "memory"); \
                             __builtin_amdgcn_s_barrier(); asm volatile("" ::: "memory"); } while (0)

// GEMM-tile LDS swizzle (64B rows, 4x16B slots): global slot gs lives at LDS slot
// t = gs ^ ((row>>1)&3). Write side pre-swizzles the GLOBAL source column (linear LDS
// dest, guide G21); read side XORs the slot. Both are lane-only constants.
//   write source slot:  (lane&3) ^ ((lane>>3)&3)     [row-in-chunk = lane>>2]
//   read slot:          (lane>>4) ^ ((lane>>1)&3)    [row = ..16k.. + (lane&15)]
// Spreads b128 fragment reads 2 lanes/granule (was 8-way pile-up on 2 granules).

// ---------------- prep_all: weight transposes + conv1 weight split + x split, one launch ----------------
// blocks [0,917): prep transpose jobs; [917,981): wprep; [981,3037): xsplit
__global__ __launch_bounds__(256) void prep_all_kernel(
    const float* s0, const float* s1, const float* s2, const float* s3, const float* s4,
    const float* s5, const float* s6, const float* s7, const float* s8, const float* s9,
    char* ws,
    const float* __restrict__ w1x, u16* __restrict__ whd, u16* __restrict__ wld,
    const float* __restrict__ x, u16* __restrict__ xh, u16* __restrict__ xl) {
  __shared__ float tile[64][65];
  int blk = blockIdx.x;
  const int tid = threadIdx.x;

  if (blk < 917) {
    const int jsrc[11] = {0,1,2,3,4, 5,5,5, 6,7, 9};
    const int jK[11]   = {512,512,512,512,128, 512,512,512, 512,2048, 64};
    const int jN[11]   = {512,512,512,128,8,   512,512,512, 2048,512, 192};
    const int jSo[11]  = {0,0,0,0,0, 0,262144,524288, 0,0, 0};
    const long long jDo[11] = {
      (long long)OFF_WTQKV, (long long)(OFF_WTQKV+524288), (long long)(OFF_WTQKV+1048576),
      (long long)OFF_G1T, (long long)OFF_G2T,
      (long long)OFF_WCT, (long long)(OFF_WCT+524288), (long long)(OFF_WCT+1048576),
      (long long)OFF_F1T, (long long)OFF_F2T, (long long)OFF_W2R};
    const int jF[11]   = {0,0,0,0,0,0,0,0,0,0,1};

    int j = 0, t = 0;
    for (int i = 0; i < 11; i++) {
      int cnt = ((jK[i] + 63) >> 6) * ((jN[i] + 63) >> 6);
      if (blk < cnt) { j = i; t = blk; break; }
      blk -= cnt;
    }
    int K = jK[j], N = jN[j];
    int ktiles = (K + 63) >> 6;
    int k0 = (t % ktiles) << 6, n0 = (t / ktiles) << 6;
    const float* SS[10] = {s0,s1,s2,s3,s4,s5,s6,s7,s8,s9};
    const float* src = SS[jsrc[j]] + jSo[j];
    for (int i = tid; i < 4096; i += 256) {
      int r = i >> 6, c = i & 63;
      float v = 0.f;
      if (k0 + r < K && n0 + c < N) v = src[(size_t)(k0 + r) * N + n0 + c];
      tile[r][c] = v;
    }
    __syncthreads();
    if (jF[j]) {
      float* dst = (float*)(ws + jDo[j]);
      for (int i = tid; i < 4096; i += 256) {
        int nr = i >> 6, kc = i & 63;
        if (n0 + nr < N && k0 + kc < K) dst[(size_t)(n0 + nr) * K + k0 + kc] = tile[kc][nr];
      }
    } else {
      u16* dst = (u16*)(ws + jDo[j]);
      for (int i = tid; i < 4096; i += 256) {
        int nr = i >> 6, kc = i & 63;
        if (n0 + nr < N && k0 + kc < K) dst[(size_t)(n0 + nr) * K + k0 + kc] = f2bf(tile[kc][nr]);
      }
    }
    return;
  }
  blk -= 917;
  if (blk < 64) {
    int c = blk;
    for (int kk = tid; kk < 2560; kk += 256) {
      int k = kk >> 9, d = kk & 511;
      float v = w1x[(size_t)c * 2560 + d * 5 + k];
      u16 h = f2bf(v);
      whd[(size_t)c * 2560 + kk] = h;
      wld[(size_t)c * 2560 + kk] = f2bf(v - bf2f(h));
    }
    return;
  }
  blk -= 64;
  {
    int idx = blk * 256 + tid;
    if (idx >= 8 * 1028 * 64) return;
    int r = idx >> 6;
    int col = (idx & 63) * 8;
    int b = r / 1028, rr = r % 1028;
    size_t dof = ((size_t)r) * 512 + col;
    if (rr < 2 || rr >= 1026) {
      u32x4 z; z.x = 0; z.y = 0; z.z = 0; z.w = 0;
      *(u32x4*)&xh[dof] = z;
      *(u32x4*)&xl[dof] = z;
      return;
    }
    const float* src = x + (((size_t)b << 10) + rr - 2) * 512 + col;
    float v[8];
    load8(src, v);
    u32 ph[4], pl[4];
#pragma unroll
    for (int i = 0; i < 4; i++) {
      u16 h0 = f2bf(v[2 * i]),     l0 = f2bf(v[2 * i]     - bf2f(f2bf(v[2 * i])));
      u16 h1 = f2bf(v[2 * i + 1]), l1 = f2bf(v[2 * i + 1] - bf2f(f2bf(v[2 * i + 1])));
      ph[i] = (u32)h0 | ((u32)h1 << 16);
      pl[i] = (u32)l0 | ((u32)l1 << 16);
    }
    u32x4 H; H.x=ph[0]; H.y=ph[1]; H.z=ph[2]; H.w=ph[3];
    u32x4 L; L.x=pl[0]; L.y=pl[1]; L.z=pl[2]; L.w=pl[3];
    *(u32x4*)&xh[dof] = H;
    *(u32x4*)&xl[dof] = L;
  }
}

// ---------------- conv1 v9: MFMA split-bf16 GEMM, 3-buffer depth-2 pipeline + LDS swizzle ----------------
__global__ __launch_bounds__(256, 6) void conv1g_kernel(
    const u16* __restrict__ xh, const u16* __restrict__ xl,
    const u16* __restrict__ wh, const u16* __restrict__ wl,
    float* __restrict__ h1p) {
  __shared__ alignas(16) u16 a_s[3][64 * 32];
  __shared__ alignas(16) u16 b_s[3][64 * 32];
  const int tid = threadIdx.x, lane = tid & 63, wid = tid >> 6;
  const int m0 = blockIdx.x * 64;
  const int z = blockIdx.z;
  const int wr = wid >> 1, wc = wid & 1;
  const int mb = wr * 32, nb = wc * 32;
  const int lrow = lane & 15;
  const int lk = ((lane >> 4) ^ ((lane >> 1) & 3)) * 8;          // swizzled read slot
  const int lr4 = lane >> 2;
  const int lc8 = ((lane & 3) ^ ((lane >> 3) & 3)) * 8;          // swizzled source slot
  const int bb = m0 >> 10, lblk = m0 & 1023;
  const size_t xrow0 = (size_t)bb * 1028;

  auto stage = [&](int buf, int kk) {
    int p = (kk >= 5120) ? 2 : (kk >= 2560) ? 1 : 0;
    int kpp = kk - p * 2560;
    int ktap = kpp >> 9, d0 = kpp & 511;
    const u16* xa = (p == 1) ? xl : xh;
    const u16* wb = (p == 2) ? wl : wh;
    gl_lds16(&xa[(xrow0 + lblk + wid * 16 + lr4 + ktap) * 512 + d0 + lc8],
             &a_s[buf][wid * 512]);
    gl_lds16(&wb[(size_t)(wid * 16 + lr4) * 2560 + kpp + lc8],
             &b_s[buf][wid * 512]);
  };

  f32x4 acc[2][2];
#pragma unroll
  for (int m = 0; m < 2; m++)
#pragma unroll
    for (int n = 0; n < 2; n++) { acc[m][n].x=0.f; acc[m][n].y=0.f; acc[m][n].z=0.f; acc[m][n].w=0.f; }

  const int kz0 = z * 1920, kz1 = kz0 + 1920;
  stage(0, kz0);
  stage(1, kz0 + 32);
  int cur = 0;
  for (int kk = kz0; kk < kz1; kk += 32) {
    if (kk + 64 < kz1) {
      int stg = cur - 1; if (stg < 0) stg = 2;   // (cur+2)%3
      stage(stg, kk + 64);
      PIPE_WAIT(4);
    } else if (kk + 32 < kz1) {
      PIPE_WAIT(2);
    } else {
      PIPE_WAIT0();
    }
    PIPE_BAR();
    bf16x8 af[2], bfr[2];
#pragma unroll
    for (int m = 0; m < 2; m++) af[m]  = *(const bf16x8*)&a_s[cur][(mb + m * 16 + lrow) * 32 + lk];
#pragma unroll
    for (int n = 0; n < 2; n++) bfr[n] = *(const bf16x8*)&b_s[cur][(nb + n * 16 + lrow) * 32 + lk];
#pragma unroll
    for (int m = 0; m < 2; m++)
#pragma unroll
      for (int n = 0; n < 2; n++)
        acc[m][n] = __builtin_amdgcn_mfma_f32_16x16x32_bf16(af[m], bfr[n], acc[m][n], 0, 0, 0);
    PIPE_BAR_LGKM();
    cur = (cur == 2) ? 0 : cur + 1;
  }
  const int r4 = (lane >> 4) * 4;
#pragma unroll
  for (int m = 0; m < 2; m++) {
#pragma unroll
    for (int n = 0; n < 2; n++) {
      const int col = nb + n * 16 + lrow;
#pragma unroll
      for (int j = 0; j < 4; j++) {
        const int row = m0 + mb + m * 16 + r4 + j;
        h1p[(size_t)z * 524288 + (size_t)row * 64 + col] = acc[m][n][j];
      }
    }
  }
}

// ------- conv23 v2: 16-l blocks (512), wave-parallel conv3, vectorized emb-add -------
__global__ __launch_bounds__(256) void conv23_kernel(
    const float* __restrict__ h1p, const float* __restrict__ b1,
    const float* __restrict__ w2r, const float* __restrict__ b2,
    const float* __restrict__ w3, const float* __restrict__ b3,
    const float* __restrict__ x, const float* __restrict__ emb,
    float* __restrict__ wmOut, float* __restrict__ x1, u16* __restrict__ x1b) {
  int seg = blockIdx.x;
  int batch = seg >> 6, l0 = (seg & 63) << 4;
  int tid = threadIdx.x, lane = tid & 63, wave = tid >> 6;
  __shared__ float hs[20][64];
  __shared__ float h2s[18][65];
  __shared__ float w3s[576];
  __shared__ int labS[16];
  for (int i = tid; i < 20 * 64; i += 256) {
    int r = i >> 6, cc = i & 63;
    int lp = l0 - 2 + r;
    float v = 0.f;
    if (lp >= 0 && lp < 1024) {
      size_t base = ((size_t)batch * 1024 + lp) * 64 + cc;
      float s = b1[cc];
#pragma unroll
      for (int q = 0; q < 4; q++) s += h1p[base + (size_t)q * 524288];
      v = fmaxf(s, 0.f);
    }
    hs[r][cc] = v;
  }
  for (int i = tid; i < 576; i += 256) w3s[i] = w3[i];
  __syncthreads();
  {
    int c = lane;
    int r0 = wave * 5;
    float a2[5];
#pragma unroll
    for (int i = 0; i < 5; i++) a2[i] = b2[c];
    for (int dd = 0; dd < 64; dd++) {
      float xv[7];
#pragma unroll
      for (int i = 0; i < 7; i++) xv[i] = (r0 + i < 20) ? hs[r0 + i][dd] : 0.f;
#pragma unroll
      for (int k = 0; k < 3; k++) {
        float wv = w2r[(size_t)(dd * 3 + k) * 64 + c];
#pragma unroll
        for (int i = 0; i < 5; i++) a2[i] += xv[i + k] * wv;
      }
    }
#pragma unroll
    for (int i = 0; i < 5; i++) {
      int hr = r0 + i;
      if (hr < 18) h2s[hr][c] = fmaxf(a2[i], 0.f);
    }
  }
  __syncthreads();
  {
    int li = tid >> 4, g = tid & 15;
    int c0 = g * 4;
    float wp[3];
#pragma unroll
    for (int jw = 0; jw < 3; jw++) {
      float a = 0.f;
#pragma unroll
      for (int k = 0; k < 3; k++)
#pragma unroll
        for (int c = 0; c < 4; c++)
          a += h2s[li + k][c0 + c] * w3s[(jw * 64 + c0 + c) * 3 + k];
      wp[jw] = a;
    }
#pragma unroll
    for (int d = 1; d < 16; d <<= 1) {
#pragma unroll
      for (int jw = 0; jw < 3; jw++) wp[jw] += __shfl_xor(wp[jw], d);
    }
    if (g == 0) {
      float wp0 = wp[0] + b3[0], wp1 = wp[1] + b3[1], wp2 = wp[2] + b3[2];
      float mx = fmaxf(wp0, fmaxf(wp1, wp2));
      float e0 = __expf(wp0 - mx), e1 = __expf(wp1 - mx), e2 = __expf(wp2 - mx);
      float inv = 1.f / (e0 + e1 + e2);
      size_t mo = ((size_t)batch * 1024 + l0 + li) * 3;
      wmOut[mo] = e0 * inv; wmOut[mo + 1] = e1 * inv; wmOut[mo + 2] = e2 * inv;
      int lb = 0; float bv = wp0;
      if (wp1 > bv) { bv = wp1; lb = 1; }
      if (wp2 > bv) { lb = 2; }
      labS[li] = lb;
    }
  }
  __syncthreads();
  for (int i = tid; i < 16 * 128; i += 256) {
    int r = i >> 7, cq = (i & 127) << 2;
    size_t gi = ((size_t)batch * 1024 + l0 + r) * 512 + cq;
    float4 xv = *(const float4*)&x[gi];
    const float* ep = &emb[(size_t)labS[r] * 512 + cq];
    float4 ev = *(const float4*)ep;
    float4 v; v.x = xv.x + ev.x; v.y = xv.y + ev.y; v.z = xv.z + ev.z; v.w = xv.w + ev.w;
    *(float4*)&x1[gi] = v;
    u32 lo = (u32)f2bf(v.x) | ((u32)f2bf(v.y) << 16);
    u32 hi = (u32)f2bf(v.z) | ((u32)f2bf(v.w) << 16);
    *(u32*)&x1b[gi] = lo;
    *(u32*)&x1b[gi + 2] = hi;
  }
}

// ---------------- generic bf16 MFMA GEMM v13: 3-buffer depth-2 + LDS swizzle + wavesim front ----------------
struct GemmArgs {
  const u16* A; const u16* Bt;
  int lda; int ldb; int K;
  const float* bias;
  u16* obf; int ldo;
  float* of32; int ldo32;
  u16* Qo; u16* Ko; u16* Vto;
  const float* bq; const float* bk; const float* bv;
  const float* wmS; float* adjS;   // fused wavesim (EPI 3, blockIdx.y == 0)
};

// EPI: 1=bias+relu->bf16, 2=bias->f32,
//      3=QKV+gates scatter (V via LDS-transpose); blockIdx.y==0 -> wavesim branch, GEMM n0=(y-1)*BN
//      6=split-K partial f32
template<int BM, int BN, int FM, int FN, int EPI>
__global__ __launch_bounds__(256, 3) void gemm_k(GemmArgs p) {
  __shared__ alignas(16) char smem[49152];   // 3 A-bufs (24KB) + 3 B-bufs (24KB); reused for V-transpose / wavesim
  u16* aS = (u16*)smem;
  u16* bS = aS + 3 * BM * 32;
  const int tid = threadIdx.x;
  const int lane = tid & 63, wid = tid >> 6;

  if constexpr (EPI == 3) {
    if (blockIdx.y == 0) {
      // ---- fused wavesim: adj[b] = wm[b] @ wm[b]^T, 64 blocks (8 b x 8 row-segs of 128) ----
      float* ms = (float*)smem;                       // [1024*3] = 12KB
      const int b = blockIdx.x >> 3;
      const int r0 = (blockIdx.x & 7) << 7;
      for (int i = tid; i < 3072; i += 256) ms[i] = p.wmS[(size_t)b * 3072 + i];
      __syncthreads();
      const int m0q = tid * 4;
      float c0 = ms[(m0q + 0) * 3],     c1 = ms[(m0q + 1) * 3],     c2 = ms[(m0q + 2) * 3],     c3 = ms[(m0q + 3) * 3];
      float d0 = ms[(m0q + 0) * 3 + 1], d1 = ms[(m0q + 1) * 3 + 1], d2 = ms[(m0q + 2) * 3 + 1], d3 = ms[(m0q + 3) * 3 + 1];
      float e0 = ms[(m0q + 0) * 3 + 2], e1 = ms[(m0q + 1) * 3 + 2], e2 = ms[(m0q + 2) * 3 + 2], e3 = ms[(m0q + 3) * 3 + 2];
      for (int r = 0; r < 128; r++) {
        float a0 = ms[(r0 + r) * 3], a1 = ms[(r0 + r) * 3 + 1], a2 = ms[(r0 + r) * 3 + 2];
        f32x4 v;
        v.x = a0 * c0 + a1 * d0 + a2 * e0;
        v.y = a0 * c1 + a1 * d1 + a2 * e1;
        v.z = a0 * c2 + a1 * d2 + a2 * e2;
        v.w = a0 * c3 + a1 * d3 + a2 * e3;
        __builtin_nontemporal_store(v, (f32x4*)&p.adjS[((size_t)b * 1024 + r0 + r) * 1024 + m0q]);
      }
      return;
    }
  }

  const int m0 = blockIdx.x * BM;
  const int n0 = (EPI == 3) ? (blockIdx.y - 1) * BN : blockIdx.y * BN;
  const int koff = (EPI == 6) ? blockIdx.z * p.K : 0;
  const int wr = wid >> 1, wc = wid & 1;
  const int mb = wr * (FM * 16), nb = wc * (FN * 16);
  const int lrow = lane & 15;
  const int lk = ((lane >> 4) ^ ((lane >> 1) & 3)) * 8;          // swizzled read slot
  constexpr int CPW_A = BM / 64;
  constexpr int CPW_B = BN / 64;
  constexpr int NL = CPW_A + CPW_B;
  const int lr4 = lane >> 2;
  const int lc8 = ((lane & 3) ^ ((lane >> 3) & 3)) * 8;          // swizzled source slot

  auto stage = [&](int buf, int k0) {
#pragma unroll
    for (int j = 0; j < CPW_A; j++) {
      int chunk = wid * CPW_A + j;
      gl_lds16(&p.A[(size_t)(m0 + chunk * 16 + lr4) * p.lda + koff + k0 + lc8],
               &aS[buf * BM * 32 + chunk * 512]);
    }
#pragma unroll
    for (int j = 0; j < CPW_B; j++) {
      int chunk = wid * CPW_B + j;
      gl_lds16(&p.Bt[(size_t)(n0 + chunk * 16 + lr4) * p.ldb + koff + k0 + lc8],
               &bS[buf * BN * 32 + chunk * 512]);
    }
  };

  f32x4 acc[FM][FN];
#pragma unroll
  for (int m = 0; m < FM; m++)
#pragma unroll
    for (int n = 0; n < FN; n++) { acc[m][n].x=0.f; acc[m][n].y=0.f; acc[m][n].z=0.f; acc[m][n].w=0.f; }

  stage(0, 0);
  stage(1, 32);
  int cur = 0;
  for (int k0 = 0; k0 < p.K; k0 += 32) {
    if (k0 + 64 < p.K) {
      int stg = cur - 1; if (stg < 0) stg = 2;   // (cur+2)%3
      stage(stg, k0 + 64);
      PIPE_WAIT(2 * NL);
    } else if (k0 + 32 < p.K) {
      PIPE_WAIT(NL);
    } else {
      PIPE_WAIT0();
    }
    PIPE_BAR();
    bf16x8 af[FM], bfr[FN];
#pragma unroll
    for (int m = 0; m < FM; m++)
      af[m] = *(const bf16x8*)&aS[cur * BM * 32 + (mb + m * 16 + lrow) * 32 + lk];
#pragma unroll
    for (int n = 0; n < FN; n++)
      bfr[n] = *(const bf16x8*)&bS[cur * BN * 32 + (nb + n * 16 + lrow) * 32 + lk];
#pragma unroll
    for (int m = 0; m < FM; m++)
#pragma unroll
      for (int n = 0; n < FN; n++)
        acc[m][n] = __builtin_amdgcn_mfma_f32_16x16x32_bf16(af[m], bfr[n], acc[m][n], 0, 0, 0);
    PIPE_BAR_LGKM();
    cur = (cur == 2) ? 0 : cur + 1;
  }
  const int r4 = (lane >> 4) * 4;

  if constexpr (EPI == 3) {
    if (n0 >= 1024 && n0 < 1536) {
      // ---- V-region block: LDS-transpose + coalesced bf16 stores ----
      float* ts = (float*)smem;              // [64 cols][128 rows], chunk-XOR swizzled (32KB <= 48KB)
      const int bb = m0 >> 10, lblk = m0 & 1023;
#pragma unroll
      for (int H = 0; H < 2; H++) {
        __syncthreads();
        if (wc == H) {
#pragma unroll
          for (int m = 0; m < FM; m++) {
#pragma unroll
            for (int n = 0; n < FN; n++) {
              const int c = n * 16 + lrow;
              const int cc = (n0 - 1024) + H * 64 + c;
              const float bvv = p.bv[cc];
#pragma unroll
              for (int j = 0; j < 4; j++) {
                const int r = mb + m * 16 + r4 + j;
                ts[c * 128 + (r ^ ((c & 3) << 2))] = acc[m][n][j] + bvv;
              }
            }
          }
        }
        __syncthreads();
        const int c = tid >> 2, seg = tid & 3;
        const int cc = (n0 - 1024) + H * 64 + c;
        const int hh = cc >> 6, dd = cc & 63;
        u16* dst = &p.Vto[((((size_t)bb * 8 + hh) * 64 + dd) << 10) + lblk + seg * 32];
        u32 pk[16];
#pragma unroll
        for (int j = 0; j < 8; j++) {
          const int chunk = seg * 8 + j;
          f32x4 v4 = *(const f32x4*)&ts[c * 128 + ((chunk ^ (c & 3)) << 2)];
          pk[2 * j + 0] = (u32)f2bf(v4.x) | ((u32)f2bf(v4.y) << 16);
          pk[2 * j + 1] = (u32)f2bf(v4.z) | ((u32)f2bf(v4.w) << 16);
        }
#pragma unroll
        for (int q = 0; q < 4; q++) {
          u32x4 sv; sv.x = pk[4 * q]; sv.y = pk[4 * q + 1]; sv.z = pk[4 * q + 2]; sv.w = pk[4 * q + 3];
          *(u32x4*)&dst[q * 8] = sv;
        }
      }
      return;
    }
  }

#pragma unroll
  for (int m = 0; m < FM; m++) {
#pragma unroll
    for (int n = 0; n < FN; n++) {
      const int col = n0 + nb + n * 16 + lrow;
#pragma unroll
      for (int j = 0; j < 4; j++) {
        const int row = m0 + mb + m * 16 + r4 + j;
        float v = acc[m][n][j];
        if constexpr (EPI == 1) {
          v += p.bias[col];
          v = fmaxf(v, 0.f);
          p.obf[(size_t)row * p.ldo + col] = f2bf(v);
        } else if constexpr (EPI == 2) {
          v += p.bias[col];
          p.of32[(size_t)row * p.ldo32 + col] = v;
        } else if constexpr (EPI == 3) {
          if (col < 512) {
            v += p.bq[col];
            p.Qo[(size_t)row * 512 + col] = f2bf(v);
          } else if (col < 1024) {
            int cc = col - 512;
            v += p.bk[cc];
            p.Ko[(size_t)row * 512 + cc] = f2bf(v);
          } else if (col >= 1536) {
            int cc = col - 1536;
            v += p.bias[cc];
            v = fmaxf(v, 0.f);
            p.obf[(size_t)row * 128 + cc] = f2bf(v);
          }
        } else if constexpr (EPI == 6) {
          if (blockIdx.z == 0) v += p.bias[col];
          p.of32[(size_t)blockIdx.z * p.ldo32 + (size_t)row * 512 + col] = v;
        }
      }
    }
  }
}

// ---------------- fused wc GEMM v6: 2-buffer counted-vmcnt pipeline + LDS swizzle ----------------
__global__ __launch_bounds__(256) void wcg_kernel(
    const u16* __restrict__ A, const u16* __restrict__ Wct,
    const float* __restrict__ wcb, const float* __restrict__ wmask,
    const float* __restrict__ wwts, float* __restrict__ out) {
  __shared__ alignas(16) u16 a_s[2][128 * 32];
  __shared__ alignas(16) u16 b_s[2][3 * 64 * 32];
  const int tid = threadIdx.x, lane = tid & 63, wid = tid >> 6;
  const int m0 = blockIdx.x * 128, n0 = blockIdx.y * 64;
  const int wr = wid >> 1, wc = wid & 1;
  const int mb = wr * 64, nb = wc * 32;
  const int lrow = lane & 15;
  const int lk = ((lane >> 4) ^ ((lane >> 1) & 3)) * 8;          // swizzled read slot
  const int lr4 = lane >> 2;
  const int lc8 = ((lane & 3) ^ ((lane >> 3) & 3)) * 8;          // swizzled source slot

  auto stage = [&](int buf, int k0) {
#pragma unroll
    for (int t = 0; t < 2; t++) {
      int ch = wid * 2 + t;
      gl_lds16(&A[(size_t)(m0 + ch * 16 + lr4) * 512 + k0 + lc8], &a_s[buf][ch * 512]);
    }
#pragma unroll
    for (int t = 0; t < 3; t++) {
      int ch = wid * 3 + t;
      int wI = ch >> 2, sub = ch & 3;
      gl_lds16(&Wct[(size_t)wI * 262144 + (size_t)(n0 + sub * 16 + lr4) * 512 + k0 + lc8],
               &b_s[buf][ch * 512]);
    }
  };

  f32x4 acc[4][2][3];
#pragma unroll
  for (int m = 0; m < 4; m++)
#pragma unroll
    for (int n = 0; n < 2; n++)
#pragma unroll
      for (int w = 0; w < 3; w++) { acc[m][n][w].x=0.f; acc[m][n][w].y=0.f; acc[m][n][w].z=0.f; acc[m][n][w].w=0.f; }

  stage(0, 0);
  int cur = 0;
  for (int k0 = 0; k0 < 512; k0 += 32) {
    if (k0 + 32 < 512) {
      stage(cur ^ 1, k0 + 32);
      PIPE_WAIT(5);
    } else {
      PIPE_WAIT0();
    }
    PIPE_BAR();
    bf16x8 af[4], bfr[3][2];
#pragma unroll
    for (int m = 0; m < 4; m++) af[m] = *(const bf16x8*)&a_s[cur][(mb + m * 16 + lrow) * 32 + lk];
#pragma unroll
    for (int w = 0; w < 3; w++)
#pragma unroll
      for (int n = 0; n < 2; n++)
        bfr[w][n] = *(const bf16x8*)&b_s[cur][(w * 64 + nb + n * 16 + lrow) * 32 + lk];
#pragma unroll
    for (int m = 0; m < 4; m++)
#pragma unroll
      for (int n = 0; n < 2; n++)
#pragma unroll
        for (int w = 0; w < 3; w++)
          acc[m][n][w] = __builtin_amdgcn_mfma_f32_16x16x32_bf16(af[m], bfr[w][n], acc[m][n][w], 0, 0, 0);
    PIPE_BAR_LGKM();
    cur ^= 1;
  }
  const float w0 = wwts[0], w1 = wwts[1], w2 = wwts[2];
  const int r4 = (lane >> 4) * 4;
#pragma unroll
  for (int m = 0; m < 4; m++) {
#pragma unroll
    for (int j = 0; j < 4; j++) {
      const int row = m0 + mb + m * 16 + r4 + j;
      float c0 = wmask[(size_t)row * 3 + 0] * w0;
      float c1 = wmask[(size_t)row * 3 + 1] * w1;
      float c2 = wmask[(size_t)row * 3 + 2] * w2;
#pragma unroll
      for (int n = 0; n < 2; n++) {
        const int col = n0 + nb + n * 16 + lrow;
        float v = c0 * (acc[m][n][0][j] + wcb[col])
                + c1 * (acc[m][n][1][j] + wcb[512 + col])
                + c2 * (acc[m][n][2][j] + wcb[1024 + col]);
        out[(size_t)row * 512 + col] = v;
      }
    }
  }
}

// ---------------- gates stage 2: sigmoid(mid @ g2 + b), N=8 ----------------
__global__ __launch_bounds__(256) void gates2_kernel(const u16* __restrict__ gmid,
    const u16* __restrict__ g2t, const float* __restrict__ g2b, float* __restrict__ gates) {
  int r0 = blockIdx.x * 64;
  __shared__ u16 ms[64][136];
  __shared__ u16 gs[8][136];
  __shared__ float gb[8];
  int tid = threadIdx.x;
  for (int i = tid; i < 1024; i += 256) {
    int r = i >> 4, ch = (i & 15) * 8;
    *(bf16x8*)&ms[r][ch] = *(const bf16x8*)&gmid[(size_t)(r0 + r) * 128 + ch];
  }
  if (tid < 128) {
    int r = tid >> 4, ch = (tid & 15) * 8;
    *(bf16x8*)&gs[r][ch] = *(const bf16x8*)&g2t[(size_t)r * 128 + ch];
  }
  if (tid < 8) gb[tid] = g2b[tid];
  __syncthreads();
  for (int o = tid; o < 512; o += 256) {
    int r = o >> 3, hh = o & 7;
    float a = gb[hh];
    for (int k = 0; k < 128; k++) a += bf2f(ms[r][k]) * bf2f(gs[hh][k]);
    gates[(size_t)(r0 + r) * 8 + hh] = 1.f / (1.f + __expf(-a));
  }
}

// ---------------- fused flash attention v4: single-buffer, 4 blocks/CU hint ----------------
__global__ __launch_bounds__(256, 4) void attn_kernel(
    const u16* __restrict__ Qb, const u16* __restrict__ Kb, const u16* __restrict__ Vt,
    const float* __restrict__ gates, const float* __restrict__ wm, float* __restrict__ ao) {
  const int g = blockIdx.x & 63, qt = blockIdx.x >> 6;
  const int b = g >> 3, h = g & 7, q0 = qt << 6;
  const int tid = threadIdx.x, lane = tid & 63, w = tid >> 6;
  __shared__ alignas(16) u16 k_s[64 * 64];
  __shared__ alignas(16) u16 v_s[64 * 64];
  __shared__ u16 p_s[4][16][72];
  __shared__ float gat[64];
  __shared__ float wmk[64][4];
  const int lrow = lane & 15, lq = lane >> 4, lk = lq * 8;
  const int qrb = q0 + w * 16;
  const int sr_ = lane >> 3, sc_ = lane & 7;
  bf16x8 qf[2];
#pragma unroll
  for (int ks = 0; ks < 2; ks++)
    qf[ks] = *(const bf16x8*)&Qb[((size_t)(b * 1024 + qrb + lrow)) * 512 + h * 64 + ks * 32 + lk];
  float wq_[4][3];
#pragma unroll
  for (int j = 0; j < 4; j++) {
    int qr = qrb + lq * 4 + j;
#pragma unroll
    for (int t = 0; t < 3; t++) wq_[j][t] = wm[((size_t)b * 1024 + qr) * 3 + t];
  }
  float lsum[4];
  f32x4 oacc[4];
#pragma unroll
  for (int j = 0; j < 4; j++) lsum[j] = 0.f;
#pragma unroll
  for (int n = 0; n < 4; n++) { oacc[n].x=0.f; oacc[n].y=0.f; oacc[n].z=0.f; oacc[n].w=0.f; }

  const u16* Kbase = Kb + ((size_t)b * 1024) * 512 + h * 64;
  const u16* Vbase = Vt + ((size_t)(b * 8 + h)) * 64 * 1024;

  for (int kt = 0; kt < 16; kt++) {
    int k0 = kt * 64;
    __syncthreads();
#pragma unroll
    for (int t = 0; t < 2; t++) {
      int ch = (w << 1) | t;
      int r = (ch << 3) | sr_;
      int srcc = ((sc_ ^ (r & 7)) << 3);
      gl_lds16(&Kbase[(size_t)(k0 + r) * 512 + srcc], &k_s[ch << 9]);
      gl_lds16(&Vbase[(size_t)r * 1024 + k0 + srcc], &v_s[ch << 9]);
    }
    if (tid < 64) {
      gat[tid] = gates[((size_t)b * 1024 + k0 + tid) * 8 + h];
#pragma unroll
      for (int t = 0; t < 3; t++) wmk[tid][t] = wm[((size_t)b * 1024 + k0 + tid) * 3 + t];
    }
    __syncthreads();
    f32x4 s[4];
#pragma unroll
    for (int n = 0; n < 4; n++) { s[n].x=0.f; s[n].y=0.f; s[n].z=0.f; s[n].w=0.f; }
#pragma unroll
    for (int ks = 0; ks < 2; ks++) {
      bf16x8 kf[4];
#pragma unroll
      for (int n = 0; n < 4; n++) {
        int kr = n * 16 + lrow;
        kf[n] = *(const bf16x8*)&k_s[kr * 64 + ((((ks << 2) | lq) ^ (kr & 7)) << 3)];
      }
#pragma unroll
      for (int n = 0; n < 4; n++)
        s[n] = __builtin_amdgcn_mfma_f32_16x16x32_bf16(qf[ks], kf[n], s[n], 0, 0, 0);
    }
    float pv[4][4];
#pragma unroll
    for (int n = 0; n < 4; n++) {
      int cl = n * 16 + lrow;
      float gg = gat[cl];
      float w0 = wmk[cl][0], w1 = wmk[cl][1], w2 = wmk[cl][2];
#pragma unroll
      for (int j = 0; j < 4; j++) {
        float wsv = wq_[j][0] * w0 + wq_[j][1] * w1 + wq_[j][2] * w2;
        float sv = s[n][j] * 0.125f;
        float e = __expf(sv * (gg + wsv) + wsv);
        pv[n][j] = e;
        lsum[j] += e;
      }
    }
#pragma unroll
    for (int n = 0; n < 4; n++)
#pragma unroll
      for (int j = 0; j < 4; j++)
        p_s[w][lq * 4 + j][n * 16 + lrow] = f2bf(pv[n][j]);
#pragma unroll
    for (int ks = 0; ks < 2; ks++) {
      bf16x8 pa, vb[4];
      pa = *(const bf16x8*)&p_s[w][lrow][ks * 32 + lk];
#pragma unroll
      for (int n = 0; n < 4; n++) {
        int vr = n * 16 + lrow;
        vb[n] = *(const bf16x8*)&v_s[vr * 64 + ((((ks << 2) | lq) ^ (vr & 7)) << 3)];
      }
#pragma unroll
      for (int n = 0; n < 4; n++)
        oacc[n] = __builtin_amdgcn_mfma_f32_16x16x32_bf16(pa, vb[n], oacc[n], 0, 0, 0);
    }
  }
  float rinv[4];
#pragma unroll
  for (int j = 0; j < 4; j++) {
    float s = lsum[j];
#pragma unroll
    for (int d = 1; d < 16; d <<= 1) s += __shfl_xor(s, d);
    rinv[j] = 1.f / s;
  }
#pragma unroll
  for (int n = 0; n < 4; n++) {
    int col = h * 64 + n * 16 + lrow;
#pragma unroll
    for (int j = 0; j < 4; j++) {
      int row = b * 1024 + qrb + lq * 4 + j;
      ao[(size_t)row * 512 + col] = oacc[n][j] * rinv[j];
    }
  }
}

// ---------------- LayerNorm helpers & fused double-LN kernels ----------------
DEVI void ln512(const float u[8], const float* __restrict__ g, const float* __restrict__ b,
                int lane, float out[8]) {
  float s = 0.f;
#pragma unroll
  for (int i = 0; i < 8; i++) s += u[i];
#pragma unroll
  for (int m = 1; m < 64; m <<= 1) s += __shfl_xor(s, m);
  float mean = s * (1.f / 512.f);
  float d[8], q = 0.f;
#pragma unroll
  for (int i = 0; i < 8; i++) { d[i] = u[i] - mean; q += d[i] * d[i]; }
#pragma unroll
  for (int m = 1; m < 64; m <<= 1) q += __shfl_xor(q, m);
  float inv = rsqrtf(q * (1.f / 512.f) + 1e-5f);
  int base = lane * 8;
#pragma unroll
  for (int i = 0; i < 8; i++) out[i] = d[i] * inv * g[base + i] + b[base + i];
}

__global__ __launch_bounds__(256) void ln1_kernel(
    const float* __restrict__ ao, const float* __restrict__ x1,
    const float* __restrict__ ga, const float* __restrict__ gb,
    const float* __restrict__ n1g, const float* __restrict__ n1b,
    float* __restrict__ x2, u16* __restrict__ x2b) {
  int row = blockIdx.x * 4 + (threadIdx.x >> 6);
  int lane = threadIdx.x & 63;
  size_t base = (size_t)row * 512 + lane * 8;
  float av[8], xv[8], u[8], t[8];
  load8(ao + base, av);
  load8(x1 + base, xv);
#pragma unroll
  for (int i = 0; i < 8; i++) u[i] = av[i] + xv[i];
  ln512(u, ga, gb, lane, t);
#pragma unroll
  for (int i = 0; i < 8; i++) u[i] = xv[i] + t[i];
  ln512(u, n1g, n1b, lane, t);
  store8(x2 + base, t);
  store8bf(x2b + base, t);
}

__global__ __launch_bounds__(256) void ln2_kernel(
    const float* __restrict__ co, const float* __restrict__ x2,
    const float* __restrict__ gc, const float* __restrict__ bc,
    const float* __restrict__ n2g, const float* __restrict__ n2b,
    float* __restrict__ x3, u16* __restrict__ x3b) {
  int row = blockIdx.x * 4 + (threadIdx.x >> 6);
  int lane = threadIdx.x & 63;
  size_t base = (size_t)row * 512 + lane * 8;
  float av[8], xv[8], u[8], t[8];
  load8(co + base, av);
#pragma unroll
  for (int i = 0; i < 8; i++) u[i] = fmaxf(av[i], 0.f);
  ln512(u, gc, bc, lane, t);
  load8(x2 + base, xv);
#pragma unroll
  for (int i = 0; i < 8; i++) u[i] = xv[i] + t[i];
  ln512(u, n2g, n2b, lane, t);
  store8(x3 + base, t);
  store8bf(x3b + base, t);
}

// ln3 v2: sums the two ffn2 split-K partials (bias already in p0)
__global__ __launch_bounds__(256) void ln3_kernel(
    const float* __restrict__ x3, const float* __restrict__ p0, const float* __restrict__ p1,
    const float* __restrict__ n3g, const float* __restrict__ n3b,
    float* __restrict__ out0) {
  int row = blockIdx.x * 4 + (threadIdx.x >> 6);
  int lane = threadIdx.x & 63;
  size_t base = (size_t)row * 512 + lane * 8;
  float a0[8], a1[8], xv[8], u[8], t[8];
  load8(x3 + base, xv);
  load8(p0 + base, a0);
  load8(p1 + base, a1);
#pragma unroll
  for (int i = 0; i < 8; i++) u[i] = xv[i] + a0[i] + a1[i];
  ln512(u, n3g, n3b, lane, t);
  store8(out0 + base, t);
}

// ---------------- host launch ----------------
extern "C" void kernel_launch(void* const* d_in, const int* in_sizes, int n_in,
                              void* d_out, int out_size, void* d_ws, size_t ws_size,
                              hipStream_t stream) {
  const float* x    = (const float*)d_in[0];
  const float* w1   = (const float*)d_in[1];
  const float* c1b  = (const float*)d_in[2];
  const float* w2   = (const float*)d_in[3];
  const float* c2b  = (const float*)d_in[4];
  const float* w3   = (const float*)d_in[5];
  const float* c3b  = (const float*)d_in[6];
  const float* emb  = (const float*)d_in[7];
  const float* wqw  = (const float*)d_in[8];
  const float* wqb  = (const float*)d_in[9];
  const float* wkw  = (const float*)d_in[10];
  const float* wkb  = (const float*)d_in[11];
  const float* wvw  = (const float*)d_in[12];
  const float* wvb  = (const float*)d_in[13];
  const float* g1w  = (const float*)d_in[14];
  const float* g1b  = (const float*)d_in[15];
  const float* g2w  = (const float*)d_in[16];
  const float* g2b  = (const float*)d_in[17];
  const float* lag  = (const float*)d_in[18];
  const float* lab  = (const float*)d_in[19];
  const float* n1g  = (const float*)d_in[20];
  const float* n1b  = (const float*)d_in[21];
  const float* lcg  = (const float*)d_in[22];
  const float* lcb  = (const float*)d_in[23];
  const float* n2g  = (const float*)d_in[24];
  const float* n2b  = (const float*)d_in[25];
  const float* n3g  = (const float*)d_in[26];
  const float* n3b  = (const float*)d_in[27];
  const float* wcw  = (const float*)d_in[28];
  const float* wcb  = (const float*)d_in[29];
  const float* wwts = (const float*)d_in[30];
  const float* f1w  = (const float*)d_in[31];
  const float* f1b  = (const float*)d_in[32];
  const float* f2w  = (const float*)d_in[33];
  const float* f2b  = (const float*)d_in[34];

  char* ws = (char*)d_ws;
  float* out0 = (float*)d_out;
  float* out1 = out0 + 4194304;   // wave_mask [8,1024,3]
  float* out2 = out1 + 24576;     // subgraph_adj [8,1024,1024]

  float* w2r_p  = (float*)(ws + OFF_W2R);
  u16*   wh_p   = (u16*)(ws + OFF_W1R);
  u16*   wl_p   = (u16*)(ws + OFF_W1R + 327680);
  u16*   xh_p   = (u16*)(ws + OFF_XH);
  u16*   xl_p   = (u16*)(ws + OFF_XL);
  float* h1p_p  = (float*)(ws + OFF_H1P);
  float* x1_p   = (float*)(ws + OFF_X1);
  u16*   x1b_p  = (u16*)(ws + OFF_X1B);
  u16*   wtqkv  = (u16*)(ws + OFF_WTQKV);
  u16*   g2t_p  = (u16*)(ws + OFF_G2T);
  u16*   wct_p  = (u16*)(ws + OFF_WCT);
  u16*   f1t_p  = (u16*)(ws + OFF_F1T);
  u16*   f2t_p  = (u16*)(ws + OFF_F2T);
  u16*   q_p    = (u16*)(ws + OFF_Q);
  u16*   k_p    = (u16*)(ws + OFF_K);
  u16*   vt_p   = (u16*)(ws + OFF_VT);
  u16*   gmid_p = (u16*)(ws + OFF_GMID);
  float* gates_p= (float*)(ws + OFF_GATES);
  float* ao_p   = (float*)(ws + OFF_AO);
  float* x2_p   = (float*)(ws + OFF_X2);
  u16*   x2b_p  = (u16*)(ws + OFF_X2B);
  float* conv_p = (float*)(ws + OFF_CONV);
  float* x3_p   = (float*)(ws + OFF_X3);
  u16*   x3b_p  = (u16*)(ws + OFF_X3B);
  u16*   fmid_p = (u16*)(ws + OFF_FMID);
  float* fp0_p  = (float*)(ws + OFF_FP0);
  float* fp1_p  = (float*)(ws + OFF_FP1);

  prep_all_kernel<<<3037, 256, 0, stream>>>(wqw, wkw, wvw, g1w, g2w, wcw, f1w, f2w, w1, w2,
                                            ws, w1, wh_p, wl_p, x, xh_p, xl_p);
  conv1g_kernel<<<dim3(128, 1, 4), 256, 0, stream>>>(xh_p, xl_p, wh_p, wl_p, h1p_p);
  conv23_kernel<<<512, 256, 0, stream>>>(h1p_p, c1b, w2r_p, c2b, w3, c3b, x, emb, out1, x1_p, x1b_p);
  {
    // QKV + gates1 merged + fused wavesim (blockIdx.y==0, dispatched first)
    GemmArgs a{}; a.A = x1b_p; a.lda = 512; a.Bt = wtqkv; a.ldb = 512; a.K = 512;
    a.Qo = q_p; a.Ko = k_p; a.Vto = vt_p; a.bq = wqb; a.bk = wkb; a.bv = wvb;
    a.bias = g1b; a.obf = gmid_p; a.ldo = 128;
    a.wmS = out1; a.adjS = out2;
    gemm_k<128,128,4,4,3><<<dim3(64,15), 256, 0, stream>>>(a);
  }
  gates2_kernel<<<128, 256, 0, stream>>>(gmid_p, g2t_p, g2b, gates_p);
  attn_kernel<<<1024, 256, 0, stream>>>(q_p, k_p, vt_p, gates_p, out1, ao_p);
  ln1_kernel<<<2048, 256, 0, stream>>>(ao_p, x1_p, lag, lab, n1g, n1b, x2_p, x2b_p);
  wcg_kernel<<<dim3(64, 8), 256, 0, stream>>>(x2b_p, wct_p, wcb, out1, wwts, conv_p);
  ln2_kernel<<<2048, 256, 0, stream>>>(conv_p, x2_p, lcg, lcb, n2g, n2b, x3_p, x3b_p);
  {
    GemmArgs a{}; a.A = x3b_p; a.lda = 512; a.Bt = f1t_p; a.ldb = 512; a.K = 512;
    a.bias = f1b; a.obf = fmid_p; a.ldo = 2048;
    gemm_k<128,128,4,4,1><<<dim3(64,16), 256, 0, stream>>>(a);
  }
  {
    // ffn2 split-K 2-way: z in {0,1} handles K window [z*1024, z*1024+1024)
    GemmArgs a{}; a.A = fmid_p; a.lda = 2048; a.Bt = f2t_p; a.ldb = 2048; a.K = 1024;
    a.bias = f2b; a.of32 = fp0_p; a.ldo32 = 4194304;
    gemm_k<128,128,4,4,6><<<dim3(64,4,2), 256, 0, stream>>>(a);
  }
  ln3_kernel<<<2048, 256, 0, stream>>>(x3_p, fp0_p, fp1_p, n3g, n3b, out0);

  (void)in_sizes; (void)n_in; (void)out_size; (void)ws_size;
}